// Round 13
// baseline (383.991 us; speedup 1.0000x reference)
//
#include <hip/hip_runtime.h>

// ---- problem constants ----
#define NIN 64
#define NOPS 1024
#define NB 2048
#define NNODES 1088            // NIN + NOPS
#define SLAB_SH 18             // node slot stride = 2048 rows * 128 B = 1<<18

// ---- workspace layout (bytes) ----
#define WS_SCHED 0u            // u64[1024] packed ops, sorted by (level, mat)
#define WS_LEV   8192u         // u32: [0]=nlev, [1]=slot of node 1087, [2]=err; +4096: u16 msta[2048]
#define WS_WT    16384u        // f16[8][64][128]  ([mat][n][k]), one-input mats zero-padded k>=64
#define WS_BIAS  147456u       // f32[512]
#define WS_SINK  149504u       // 64KB junk-lane store sink (raced garbage, never read)
#define WS_NODES 215040u       // f16[cap][2048][64] slot slabs

typedef unsigned int u32;
typedef unsigned short u16;
typedef unsigned long long u64;
typedef _Float16 f16;
typedef _Float16 f16x8 __attribute__((ext_vector_type(8)));
typedef _Float16 f16x4 __attribute__((ext_vector_type(4)));
typedef float f32x4 __attribute__((ext_vector_type(4)));

#define MFMA16(a, b, c) __builtin_amdgcn_mfma_f32_16x16x32_f16((a), (b), (c), 0, 0, 0)

// sched word bits (k_main uses 0-10 slot1 | 11-21 slot2 | 25-35 outslot)

// ---------------- schedule: levels + (level,mat) sort + liveness slot allocation ----------------
__global__ __launch_bounds__(1024) void k_sched(const int* __restrict__ wxv,
                                                const int* __restrict__ in1v,
                                                const int* __restrict__ in2v,
                                                char* __restrict__ ws, int cap) {
  __shared__ int s1[NOPS], s2[NOPS], sw[NOPS], slv[NOPS];
  __shared__ int lcnt[132];
  __shared__ int cnt2[1032];
  __shared__ u64 s_pack[NOPS];
  __shared__ int dl[NNODES], slot_of[NNODES], stk[NNODES];
  __shared__ int s_flag, s_nlev, s_top, s_next;
  const int j = threadIdx.x;
  s1[j] = in1v[j]; s2[j] = in2v[j]; sw[j] = wxv[j]; slv[j] = 1;
  if (j < 132) lcnt[j] = 0;
  if (j < 1032) cnt2[j] = 0;
  __syncthreads();
  // monotone relaxation: lvl[j] = 1 + max(lvl(parents)); one-input ops depend only on in1
  for (int it = 0; it < NOPS + 1; ++it) {
    if (j == 0) s_flag = 0;
    __syncthreads();
    int p1 = s1[j];
    int l1 = (p1 >= NIN) ? slv[p1 - NIN] : 0;
    int l2 = 0;
    if (sw[j] >= 4) { int p2 = s2[j]; l2 = (p2 >= NIN) ? slv[p2 - NIN] : 0; }
    int nl = 1 + (l1 > l2 ? l1 : l2);
    if (nl != slv[j]) { slv[j] = nl; s_flag = 1; }
    __syncthreads();
    int f = s_flag;
    __syncthreads();
    if (!f) break;
  }
  if (j == 0) s_nlev = 0;
  __syncthreads();
  atomicMax(&s_nlev, slv[j]);
  __syncthreads();
  u32* wl = (u32*)(ws + WS_LEV);
  const int nlev = s_nlev;
  if (nlev > 127) { if (j == 0) { wl[0] = 0; wl[1] = 0; wl[2] = 1; } return; }
  atomicAdd(&lcnt[slv[j]], 1);
  atomicAdd(&cnt2[slv[j] * 8 + sw[j]], 1);
  __syncthreads();
  if (j == 0) {
    int acc = 0;
    for (int L = 1; L <= nlev; ++L) { int c = lcnt[L]; lcnt[L] = acc; acc += c; }  // level bases
  }
  __syncthreads();
  int base = -1;
  if (j >= 8 && j < (nlev + 1) * 8) {
    int L = j >> 3, mm = j & 7;
    int s = lcnt[L];
    for (int q = 0; q < mm; ++q) s += cnt2[L * 8 + q];
    base = s;
  }
  u16* msta = (u16*)(ws + WS_LEV + 4096);
  for (int t = j; t < 2048; t += 1024) msta[t] = (u16)NOPS;
  __syncthreads();
  if (base >= 0) { cnt2[j] = base; msta[j] = (u16)base; }   // cnt2 becomes the cursor
  __syncthreads();
  { int slot = atomicAdd(&cnt2[slv[j] * 8 + sw[j]], 1);
    u64 p = (u64)(u32)s1[j] | ((u64)(u32)s2[j] << 11) | ((u64)(u32)sw[j] << 22) | ((u64)(u32)j << 25);
    s_pack[slot] = p; }
  // death levels
  for (int t = j; t < NNODES; t += 1024) dl[t] = (t < NIN) ? 0 : slv[t - NIN];
  __syncthreads();
  atomicMax(&dl[s1[j]], slv[j]);
  if (sw[j] >= 4) atomicMax(&dl[s2[j]], slv[j]);
  __syncthreads();
  if (j == 0) { dl[NNODES - 1] = nlev + 1; s_top = 0; s_next = NIN; }
  if (j < NIN) slot_of[j] = j;
  __syncthreads();
  // greedy interval-coloring by level: free (dl == L-1) then allocate (slv == L)
  for (int L = 1; L <= nlev; ++L) {
    for (int t = j; t < NNODES; t += 1024)
      if (dl[t] == L - 1) { int p = atomicAdd(&s_top, 1); stk[p] = slot_of[t]; }
    __syncthreads();
    if (slv[j] == L) {
      int p = atomicSub(&s_top, 1);
      int s;
      if (p >= 1) s = stk[p - 1]; else s = atomicAdd(&s_next, 1);
      slot_of[NIN + j] = s;
    }
    __syncthreads();
    if (j == 0 && s_top < 0) s_top = 0;
    __syncthreads();
  }
  // rewrite schedule entries with slot indices
  {
    u64 m = s_pack[j];
    int i1n = (int)(m & 2047u), i2n = (int)((m >> 11) & 2047u);
    u32 wxn = (u32)((m >> 22) & 7u);
    int opn = (int)((m >> 25) & 2047u);
    if (wxn < 4) i2n = i1n;           // one-input: i2:=i1 (guaranteed-live slot)
    u32 s1slot = (u32)slot_of[i1n];
    u32 s2slot = (u32)slot_of[i2n];
    u64 nm = (u64)s1slot | ((u64)s2slot << 11) | ((u64)wxn << 22)
           | ((u64)(u32)slot_of[NIN + opn] << 25);
    ((u64*)(ws + WS_SCHED))[j] = nm;
  }
  if (j == 0) {
    wl[0] = (u32)nlev;
    wl[1] = (u32)slot_of[NNODES - 1];
    wl[2] = (s_next > cap) ? 1u : 0u;
  }
}

// ---------------- weights: unify + zero-pad + transpose to [mat][n][k], fp16 ----------------
__global__ __launch_bounds__(256) void k_weights(const float* __restrict__ oW,
                                                 const float* __restrict__ ob,
                                                 const float* __restrict__ tW,
                                                 const float* __restrict__ tb,
                                                 char* __restrict__ ws) {
  f16* wt = (f16*)(ws + WS_WT);
  int t = blockIdx.x * 256 + threadIdx.x;
  #pragma unroll
  for (int q = 0; q < 4; ++q) {
    int e = t * 4 + q;                       // e = mat*8192 + n*128 + k
    int mat = e >> 13, n = (e >> 7) & 63, k = e & 127;
    float v;
    if (mat < 4) v = (k < 64) ? oW[mat * 4096 + k * 64 + n] : 0.f;
    else         v = tW[(mat - 4) * 8192 + k * 64 + n];
    wt[e] = (f16)v;
  }
  if (blockIdx.x == 0) {
    float* bs = (float*)(ws + WS_BIAS);
    for (int q = threadIdx.x; q < 512; q += 256)
      bs[q] = (q < 256) ? ob[q] : tb[q - 256];
  }
}

// ---------------- leaves: embedding gather -> slots 0..63 (fp16, vectorized) ----------------
__global__ __launch_bounds__(256) void k_leaves(const int* __restrict__ ids,
                                                const float* __restrict__ emb,
                                                char* __restrict__ ws) {
  int p = blockIdx.x * 256 + threadIdx.x;      // 131072 (i,b) pairs
  int i = p >> 11, b = p & 2047;
  int id = ids[b * 64 + i];
  const f32x4* src = (const f32x4*)(emb + (u32)id * 64u);
  f16x8* dst = (f16x8*)(ws + WS_NODES + ((u32)i << SLAB_SH) + (u32)b * 128u);
  #pragma unroll
  for (int q = 0; q < 8; ++q) {
    f32x4 lo = src[2 * q], hi = src[2 * q + 1];
    f16x8 v = { (f16)lo.x, (f16)lo.y, (f16)lo.z, (f16)lo.w,
                (f16)hi.x, (f16)hi.y, (f16)hi.z, (f16)hi.w };
    dst[q] = v;
  }
}

// ---------------- main: mat waves, straight-line chunks, sink-store, all-global ----------------
__global__ __launch_bounds__(1024, 4) void k_main(char* __restrict__ ws) {
  __shared__ u64 s_sched[NOPS];   // 8 KB
  __shared__ u16 s_msta[2048];    // 4 KB
  const int tid = threadIdx.x;
  const u32* wl = (const u32*)(ws + WS_LEV);
  if (wl[2]) return;               // uniform early-out before any barrier
  s_sched[tid] = ((const u64*)(ws + WS_SCHED))[tid];
  ((u32*)s_msta)[tid] = ((const u32*)(ws + WS_LEV + 4096))[tid & 1023];
  const int nlev = (int)wl[0];

  const int lane = tid & 63;
  const int w   = tid >> 6;        // 16 waves
  const int m   = w & 7;           // owned weight matrix (m<4 => one-input)
  const int nh  = w >> 3;          // column half
  const int lhi = lane >> 4, llo = lane & 15;
  const int r0  = blockIdx.x * 8;  // 256 blocks x 8 batch rows
  char* nodes = ws + WS_NODES;

  // W cache: (32 cols x 128 k) slice of mat m; one-input waves only k<64 half
  const f16* wp = (const f16*)(ws + WS_WT) + m * 8192 + (nh * 32 + llo) * 128 + lhi * 8;
  const f16x8 W00 = *(const f16x8*)(wp +        0), W01 = *(const f16x8*)(wp +       32),
              W10 = *(const f16x8*)(wp + 2048 + 0), W11 = *(const f16x8*)(wp + 2048 + 32);
  f16x8 W02 = {}, W03 = {}, W12 = {}, W13 = {};
  if (m >= 4) {
    W02 = *(const f16x8*)(wp +       64); W03 = *(const f16x8*)(wp +       96);
    W12 = *(const f16x8*)(wp + 2048 + 64); W13 = *(const f16x8*)(wp + 2048 + 96);
  }
  const float* bsp = (const float*)(ws + WS_BIAS) + m * 64 + nh * 32 + lhi * 4;
  const f32x4 B0 = *(const f32x4*)(bsp), B1 = *(const f32x4*)(bsp + 16);
  __syncthreads();

  const u32 a_off  = (u32)((r0 + (llo & 7)) * 128 + lhi * 16);
  const u32 st_off = (u32)((r0 + llo) * 128 + (nh * 32 + lhi * 4) * 2);
  char* sinkp = ws + WS_SINK + (u32)tid * 64u;   // raced garbage region, never read

  auto load1 = [&](u64 md, f16x8& a0, f16x8& a1) {
    const char* b1 = nodes + ((u64)((u32)md & 2047u) << SLAB_SH) + a_off;
    a0 = *(const f16x8*)(b1);
    a1 = *(const f16x8*)(b1 + 64);
  };
  auto load2 = [&](u64 md, f16x8& a2, f16x8& a3) {
    const char* b2 = nodes + ((u64)(((u32)(md >> 11)) & 2047u) << SLAB_SH) + a_off;
    a2 = *(const f16x8*)(b2);
    a3 = *(const f16x8*)(b2 + 64);
  };
  // unconditional compute + unconditional store (address-selected): single basic block
  auto compT = [&](u64 md, const f16x8& a0, const f16x8& a1,
                   const f16x8& a2, const f16x8& a3) {
    f32x4 c0 = B0, c1 = B1;
    __builtin_amdgcn_s_setprio(1);
    c0 = MFMA16(W00, a0, c0); c0 = MFMA16(W01, a1, c0);
    c0 = MFMA16(W02, a2, c0); c0 = MFMA16(W03, a3, c0);
    c1 = MFMA16(W10, a0, c1); c1 = MFMA16(W11, a1, c1);
    c1 = MFMA16(W12, a2, c1); c1 = MFMA16(W13, a3, c1);
    __builtin_amdgcn_s_setprio(0);
    f16x4 r0v = { (f16)(c0.x > 0.f ? c0.x : 0.f), (f16)(c0.y > 0.f ? c0.y : 0.f),
                  (f16)(c0.z > 0.f ? c0.z : 0.f), (f16)(c0.w > 0.f ? c0.w : 0.f) };
    f16x4 r1v = { (f16)(c1.x > 0.f ? c1.x : 0.f), (f16)(c1.y > 0.f ? c1.y : 0.f),
                  (f16)(c1.z > 0.f ? c1.z : 0.f), (f16)(c1.w > 0.f ? c1.w : 0.f) };
    char* real = nodes + (((u64)((md >> 25) & 2047u)) << SLAB_SH) + st_off;
    char* st = (llo < 8) ? real : sinkp;       // address select, no branch
    *(f16x4*)(st)      = r0v;
    *(f16x4*)(st + 32) = r1v;
  };
  auto compO = [&](u64 md, const f16x8& a0, const f16x8& a1) {
    f32x4 c0 = B0, c1 = B1;
    __builtin_amdgcn_s_setprio(1);
    c0 = MFMA16(W00, a0, c0); c0 = MFMA16(W01, a1, c0);
    c1 = MFMA16(W10, a0, c1); c1 = MFMA16(W11, a1, c1);
    __builtin_amdgcn_s_setprio(0);
    f16x4 r0v = { (f16)(c0.x > 0.f ? c0.x : 0.f), (f16)(c0.y > 0.f ? c0.y : 0.f),
                  (f16)(c0.z > 0.f ? c0.z : 0.f), (f16)(c0.w > 0.f ? c0.w : 0.f) };
    f16x4 r1v = { (f16)(c1.x > 0.f ? c1.x : 0.f), (f16)(c1.y > 0.f ? c1.y : 0.f),
                  (f16)(c1.z > 0.f ? c1.z : 0.f), (f16)(c1.w > 0.f ? c1.w : 0.f) };
    char* real = nodes + (((u64)((md >> 25) & 2047u)) << SLAB_SH) + st_off;
    char* st = (llo < 8) ? real : sinkp;
    *(f16x4*)(st)      = r0v;
    *(f16x4*)(st + 32) = r1v;
  };

  for (int L = 1; L <= nlev; ++L) {
    int k0 = (int)s_msta[L * 8 + m];
    int k1 = (int)s_msta[L * 8 + m + 1];
    k0 = __builtin_amdgcn_readfirstlane(k0);
    k1 = __builtin_amdgcn_readfirstlane(k1);
    const int ke = k1 - 1;
    if (m < 4) {
      // one-input: chunks of 8 clamped ops; duplicates recompute identical bytes (safe)
      for (int base = k0; base < k1; base += 8) {
        int j1 = base + 1 > ke ? ke : base + 1;
        int j2 = base + 2 > ke ? ke : base + 2;
        int j3 = base + 3 > ke ? ke : base + 3;
        int j4 = base + 4 > ke ? ke : base + 4;
        int j5 = base + 5 > ke ? ke : base + 5;
        int j6 = base + 6 > ke ? ke : base + 6;
        int j7 = base + 7 > ke ? ke : base + 7;
        u64 m0 = s_sched[base], m1 = s_sched[j1], m2 = s_sched[j2], m3 = s_sched[j3],
            m4 = s_sched[j4],   m5 = s_sched[j5], m6 = s_sched[j6], m7 = s_sched[j7];
        f16x8 a00, a01, a10, a11, a20, a21, a30, a31,
              a40, a41, a50, a51, a60, a61, a70, a71;
        load1(m0, a00, a01); load1(m1, a10, a11); load1(m2, a20, a21); load1(m3, a30, a31);
        load1(m4, a40, a41); load1(m5, a50, a51); load1(m6, a60, a61); load1(m7, a70, a71);
        __builtin_amdgcn_sched_barrier(0);     // loads stay above computes
        compO(m0, a00, a01); compO(m1, a10, a11);
        compO(m2, a20, a21); compO(m3, a30, a31);
        compO(m4, a40, a41); compO(m5, a50, a51);
        compO(m6, a60, a61); compO(m7, a70, a71);
      }
    } else {
      // two-input: chunks of 4 clamped ops
      for (int base = k0; base < k1; base += 4) {
        int j1 = base + 1 > ke ? ke : base + 1;
        int j2 = base + 2 > ke ? ke : base + 2;
        int j3 = base + 3 > ke ? ke : base + 3;
        u64 m0 = s_sched[base], m1 = s_sched[j1], m2 = s_sched[j2], m3 = s_sched[j3];
        f16x8 a00, a01, a02, a03, a10, a11, a12, a13,
              a20, a21, a22, a23, a30, a31, a32, a33;
        load1(m0, a00, a01); load2(m0, a02, a03);
        load1(m1, a10, a11); load2(m1, a12, a13);
        load1(m2, a20, a21); load2(m2, a22, a23);
        load1(m3, a30, a31); load2(m3, a32, a33);
        __builtin_amdgcn_sched_barrier(0);
        compT(m0, a00, a01, a02, a03);
        compT(m1, a10, a11, a12, a13);
        compT(m2, a20, a21, a22, a23);
        compT(m3, a30, a31, a32, a33);
      }
    }
    __syncthreads();   // level boundary: drains stores (L2-visible), orders RAW
  }
}

// ---------------- final: out[b] = nodes[slot1087][b] . final_W + final_b ----------------
__global__ __launch_bounds__(256) void k_final(const float* __restrict__ fw,
                                               const float* __restrict__ fb,
                                               const char* __restrict__ ws,
                                               float* __restrict__ out) {
  __shared__ float s_fw[64];
  int t = threadIdx.x;
  if (t < 64) s_fw[t] = fw[t];
  __syncthreads();
  int b = blockIdx.x * 256 + t;
  const u32* wl = (const u32*)(ws + WS_LEV);
  if (wl[2]) { out[b] = 0.f; return; }
  u32 slot = wl[1];
  const f16x8* last = (const f16x8*)(ws + WS_NODES + ((u64)slot << SLAB_SH) + (u32)b * 128u);
  float acc = fb[0];
  #pragma unroll
  for (int q = 0; q < 8; ++q) {
    f16x8 v = last[q];
    #pragma unroll
    for (int e = 0; e < 8; ++e) acc += (float)v[e] * s_fw[q * 8 + e];
  }
  out[b] = acc;
}

extern "C" void kernel_launch(void* const* d_in, const int* in_sizes, int n_in,
                              void* d_out, int out_size, void* d_ws, size_t ws_size,
                              hipStream_t stream) {
  const int*   ids = (const int*)d_in[0];
  const int*   wx  = (const int*)d_in[1];
  const int*   i1  = (const int*)d_in[2];
  const int*   i2  = (const int*)d_in[3];
  const float* emb = (const float*)d_in[4];
  const float* ob  = (const float*)d_in[6];
  const float* oW  = (const float*)d_in[5];
  const float* tW  = (const float*)d_in[7];
  const float* tb  = (const float*)d_in[8];
  const float* fw  = (const float*)d_in[9];
  const float* fb  = (const float*)d_in[10];
  char* ws = (char*)d_ws;
  float* out = (float*)d_out;

  int cap = (int)((ws_size > (size_t)WS_NODES) ? ((ws_size - WS_NODES) >> SLAB_SH) : 0);
  if (cap < 80) return;
  if (cap > 2047) cap = 2047;

  hipLaunchKernelGGL(k_sched,   dim3(1),   dim3(1024), 0, stream, wx, i1, i2, ws, cap);
  hipLaunchKernelGGL(k_weights, dim3(64),  dim3(256),  0, stream, oW, ob, tW, tb, ws);
  hipLaunchKernelGGL(k_leaves,  dim3(512), dim3(256),  0, stream, ids, emb, ws);
  hipLaunchKernelGGL(k_main,    dim3(256), dim3(1024), 0, stream, ws);
  hipLaunchKernelGGL(k_final,   dim3(8),   dim3(256),  0, stream, fw, fb, ws, out);
}

// Round 14
// 219.266 us; speedup vs baseline: 1.7513x; 1.7513x over previous
//
#include <hip/hip_runtime.h>

// ---- problem constants ----
#define NIN 64
#define NOPS 1024
#define NB 2048
#define NNODES 1088            // NIN + NOPS
#define SLAB_SH 18             // node slot stride = 2048 rows * 128 B = 1<<18

// ---- workspace layout (bytes) ----
#define WS_SCHED 0u            // u64[1024] packed ops, sorted by (level, mat)
#define WS_LEV   8192u         // u32: [0]=nlev, [1]=slot of node 1087, [2]=err; +4096: u16 msta[2048]
#define WS_WT    16384u        // f16[8][64][128]  ([mat][n][k]), one-input mats zero-padded k>=64
#define WS_BIAS  147456u       // f32[512]
#define WS_NODES 163840u       // f16[cap][2048][64] slot slabs

// ---- k_main dynamic LDS layout (bytes) ----
// 2 level-buffers x 64 lines x 512B (4 rows x 64 cols fp16, swizzled) + tables
#define LM_LINES 0u            // 65536
#define LM_SCHED 65536u        // u64[1024] = 8KB
#define LM_MSTA  73728u        // u16[2048] = 4KB
#define LM_TOTAL 77824u        // 76KB -> 2 blocks/CU

typedef unsigned int u32;
typedef unsigned short u16;
typedef unsigned long long u64;
typedef _Float16 f16;
typedef _Float16 f16x8 __attribute__((ext_vector_type(8)));
typedef _Float16 f16x4 __attribute__((ext_vector_type(4)));
typedef float f32x4 __attribute__((ext_vector_type(4)));

#define MFMA16(a, b, c) __builtin_amdgcn_mfma_f32_16x16x32_f16((a), (b), (c), 0, 0, 0)

// sched word bits (R8 layout):
//  0-10 slot1 | 11-21 slot2 | 22-24 wx | 25-35 outslot
//  36-42 pos1, 43 fresh1 | 44-50 pos2, 51 fresh2 | 52-58 outpos, 59 ldsout | 60 globalout

// ---------------- schedule: levels + (level,mat) sort + liveness slots + LDS-edge marking ----------------
__global__ __launch_bounds__(1024) void k_sched(const int* __restrict__ wxv,
                                                const int* __restrict__ in1v,
                                                const int* __restrict__ in2v,
                                                char* __restrict__ ws, int cap) {
  __shared__ int s1[NOPS], s2[NOPS], sw[NOPS], slv[NOPS];
  __shared__ int lcnt[132];
  __shared__ int cnt2[1032];
  __shared__ u64 s_pack[NOPS];
  __shared__ int dl[NNODES], slot_of[NNODES], stk[NNODES];
  __shared__ int opPos[NOPS];
  __shared__ unsigned char needG[NOPS];
  __shared__ int s_flag, s_nlev, s_top, s_next;
  const int j = threadIdx.x;
  s1[j] = in1v[j]; s2[j] = in2v[j]; sw[j] = wxv[j]; slv[j] = 1;
  needG[j] = 0;
  if (j < 132) lcnt[j] = 0;
  if (j < 1032) cnt2[j] = 0;
  __syncthreads();
  for (int it = 0; it < NOPS + 1; ++it) {
    if (j == 0) s_flag = 0;
    __syncthreads();
    int p1 = s1[j];
    int l1 = (p1 >= NIN) ? slv[p1 - NIN] : 0;
    int l2 = 0;
    if (sw[j] >= 4) { int p2 = s2[j]; l2 = (p2 >= NIN) ? slv[p2 - NIN] : 0; }
    int nl = 1 + (l1 > l2 ? l1 : l2);
    if (nl != slv[j]) { slv[j] = nl; s_flag = 1; }
    __syncthreads();
    int f = s_flag;
    __syncthreads();
    if (!f) break;
  }
  if (j == 0) s_nlev = 0;
  __syncthreads();
  atomicMax(&s_nlev, slv[j]);
  __syncthreads();
  u32* wl = (u32*)(ws + WS_LEV);
  const int nlev = s_nlev;
  if (nlev > 127) { if (j == 0) { wl[0] = 0; wl[1] = 0; wl[2] = 1; } return; }
  atomicAdd(&lcnt[slv[j]], 1);
  atomicAdd(&cnt2[slv[j] * 8 + sw[j]], 1);
  __syncthreads();
  if (j == 0) {
    int acc = 0;
    for (int L = 1; L <= nlev; ++L) { int c = lcnt[L]; lcnt[L] = acc; acc += c; }
  }
  __syncthreads();
  int base = -1;
  if (j >= 8 && j < (nlev + 1) * 8) {
    int L = j >> 3, mm = j & 7;
    int s = lcnt[L];
    for (int q = 0; q < mm; ++q) s += cnt2[L * 8 + q];
    base = s;
  }
  u16* msta = (u16*)(ws + WS_LEV + 4096);
  for (int t = j; t < 2048; t += 1024) msta[t] = (u16)NOPS;
  __syncthreads();
  if (base >= 0) { cnt2[j] = base; msta[j] = (u16)base; }
  __syncthreads();
  { int slot = atomicAdd(&cnt2[slv[j] * 8 + sw[j]], 1);
    u64 p = (u64)(u32)s1[j] | ((u64)(u32)s2[j] << 11) | ((u64)(u32)sw[j] << 22) | ((u64)(u32)j << 25);
    s_pack[slot] = p;
    opPos[j] = slot - lcnt[slv[j]]; }
  __syncthreads();
  if (j == NOPS - 1) needG[j] = 1;
  { int L = slv[j];
    int i1n = s1[j];
    if (i1n >= NIN) { int p = i1n - NIN; if (!(slv[p] == L - 1 && opPos[p] < 64)) needG[p] = 1; }
    if (sw[j] >= 4) {
      int i2n = s2[j];
      if (i2n >= NIN) { int p = i2n - NIN; if (!(slv[p] == L - 1 && opPos[p] < 64)) needG[p] = 1; }
    } }
  for (int t = j; t < NNODES; t += 1024) dl[t] = (t < NIN) ? 0 : slv[t - NIN];
  __syncthreads();
  atomicMax(&dl[s1[j]], slv[j]);
  if (sw[j] >= 4) atomicMax(&dl[s2[j]], slv[j]);
  __syncthreads();
  if (j == 0) { dl[NNODES - 1] = nlev + 1; s_top = 0; s_next = NIN; }
  if (j < NIN) slot_of[j] = j;
  __syncthreads();
  for (int L = 1; L <= nlev; ++L) {
    for (int t = j; t < NNODES; t += 1024)
      if (dl[t] == L - 1) { int p = atomicAdd(&s_top, 1); stk[p] = slot_of[t]; }
    __syncthreads();
    if (slv[j] == L) {
      int p = atomicSub(&s_top, 1);
      int s;
      if (p >= 1) s = stk[p - 1]; else s = atomicAdd(&s_next, 1);
      slot_of[NIN + j] = s;
    }
    __syncthreads();
    if (j == 0 && s_top < 0) s_top = 0;
    __syncthreads();
  }
  {
    u64 m = s_pack[j];
    int i1n = (int)(m & 2047u), i2n = (int)((m >> 11) & 2047u);
    u32 wxn = (u32)((m >> 22) & 7u);
    int opn = (int)((m >> 25) & 2047u);
    int Lop = slv[opn];
    int two = (wxn >= 4);
    if (!two) i2n = i1n;
    u32 f1 = 0, p1 = 0, f2 = 0, p2 = 0;
    if (i1n >= NIN) { int p = i1n - NIN;
      if (slv[p] == Lop - 1 && opPos[p] < 64) { f1 = 1; p1 = (u32)opPos[p]; } }
    if (i2n >= NIN) { int p = i2n - NIN;
      if (slv[p] == Lop - 1 && opPos[p] < 64) { f2 = 1; p2 = (u32)opPos[p]; } }
    u32 op_pos = (u32)opPos[opn];
    u32 ldsout = (op_pos < 64) ? 1u : 0u;
    u32 gout   = needG[opn] ? 1u : 0u;
    u32 s1slot = (u32)slot_of[i1n];
    u32 s2slot = (u32)slot_of[i2n];
    u64 nm = (u64)s1slot | ((u64)s2slot << 11) | ((u64)wxn << 22)
           | ((u64)(u32)slot_of[NIN + opn] << 25)
           | ((u64)p1 << 36) | ((u64)f1 << 43)
           | ((u64)p2 << 44) | ((u64)f2 << 51)
           | ((u64)(op_pos & 63u) << 52) | ((u64)ldsout << 59)
           | ((u64)gout << 60);
    ((u64*)(ws + WS_SCHED))[j] = nm;
  }
  if (j == 0) {
    wl[0] = (u32)nlev;
    wl[1] = (u32)slot_of[NNODES - 1];
    wl[2] = (s_next > cap) ? 1u : 0u;
  }
}

// ---------------- weights: unify + zero-pad + transpose to [mat][n][k], fp16 ----------------
__global__ __launch_bounds__(256) void k_weights(const float* __restrict__ oW,
                                                 const float* __restrict__ ob,
                                                 const float* __restrict__ tW,
                                                 const float* __restrict__ tb,
                                                 char* __restrict__ ws) {
  f16* wt = (f16*)(ws + WS_WT);
  int t = blockIdx.x * 256 + threadIdx.x;
  #pragma unroll
  for (int q = 0; q < 4; ++q) {
    int e = t * 4 + q;                       // e = mat*8192 + n*128 + k
    int mat = e >> 13, n = (e >> 7) & 63, k = e & 127;
    float v;
    if (mat < 4) v = (k < 64) ? oW[mat * 4096 + k * 64 + n] : 0.f;
    else         v = tW[(mat - 4) * 8192 + k * 64 + n];
    wt[e] = (f16)v;
  }
  if (blockIdx.x == 0) {
    float* bs = (float*)(ws + WS_BIAS);
    for (int q = threadIdx.x; q < 512; q += 256)
      bs[q] = (q < 256) ? ob[q] : tb[q - 256];
  }
}

// ---------------- leaves: embedding gather -> slots 0..63 (fp16, vectorized) ----------------
__global__ __launch_bounds__(256) void k_leaves(const int* __restrict__ ids,
                                                const float* __restrict__ emb,
                                                char* __restrict__ ws) {
  int p = blockIdx.x * 256 + threadIdx.x;      // 131072 (i,b) pairs
  int i = p >> 11, b = p & 2047;
  int id = ids[b * 64 + i];
  const f32x4* src = (const f32x4*)(emb + (u32)id * 64u);
  f16x8* dst = (f16x8*)(ws + WS_NODES + ((u32)i << SLAB_SH) + (u32)b * 128u);
  #pragma unroll
  for (int q = 0; q < 8; ++q) {
    f32x4 lo = src[2 * q], hi = src[2 * q + 1];
    f16x8 v = { (f16)lo.x, (f16)lo.y, (f16)lo.z, (f16)lo.w,
                (f16)hi.x, (f16)hi.y, (f16)hi.z, (f16)hi.w };
    dst[q] = v;
  }
}

// ---------------- main: 512 blocks x 512 thr (8 mat-waves, full-width), 2 blocks/CU ----------------
__global__ __launch_bounds__(512, 4) void k_main(char* __restrict__ ws) {
  extern __shared__ char lds[];
  const int tid = threadIdx.x;
  const u32* wl = (const u32*)(ws + WS_LEV);
  if (wl[2]) return;               // uniform early-out before any barrier
  for (int t = tid; t < NOPS; t += 512)
    ((u64*)(lds + LM_SCHED))[t] = ((const u64*)(ws + WS_SCHED))[t];
  for (int t = tid; t < 1024; t += 512)
    ((u32*)(lds + LM_MSTA))[t] = ((const u32*)(ws + WS_LEV + 4096))[t];
  const int nlev = (int)wl[0];

  const int lane = tid & 63;
  const int m   = tid >> 6;        // 8 waves, wave = its matrix (m<4 => one-input)
  const int lhi = lane >> 4, llo = lane & 15;
  const int r0  = blockIdx.x * 4;  // 512 blocks x 4 batch rows
  char* nodes = ws + WS_NODES;

  // W cache: FULL (64 cols x 128 k) slice of mat m; one-input waves only k<64 half
  const f16* wp = (const f16*)(ws + WS_WT) + m * 8192 + llo * 128 + lhi * 8;
  const f16x8 W00 = *(const f16x8*)(wp +        0), W01 = *(const f16x8*)(wp +       32),
              W10 = *(const f16x8*)(wp + 2048 + 0), W11 = *(const f16x8*)(wp + 2048 + 32),
              W20 = *(const f16x8*)(wp + 4096 + 0), W21 = *(const f16x8*)(wp + 4096 + 32),
              W30 = *(const f16x8*)(wp + 6144 + 0), W31 = *(const f16x8*)(wp + 6144 + 32);
  f16x8 W02 = {}, W03 = {}, W12 = {}, W13 = {}, W22 = {}, W23 = {}, W32 = {}, W33 = {};
  if (m >= 4) {
    W02 = *(const f16x8*)(wp +        64); W03 = *(const f16x8*)(wp +        96);
    W12 = *(const f16x8*)(wp + 2048 + 64); W13 = *(const f16x8*)(wp + 2048 + 96);
    W22 = *(const f16x8*)(wp + 4096 + 64); W23 = *(const f16x8*)(wp + 4096 + 96);
    W32 = *(const f16x8*)(wp + 6144 + 64); W33 = *(const f16x8*)(wp + 6144 + 96);
  }
  const float* bsp = (const float*)(ws + WS_BIAS) + m * 64 + lhi * 4;
  const f32x4 B0 = *(const f32x4*)(bsp),      B1 = *(const f32x4*)(bsp + 16),
              B2 = *(const f32x4*)(bsp + 32), B3 = *(const f32x4*)(bsp + 48);
  __syncthreads();

  const u64* s_sched = (const u64*)(lds + LM_SCHED);
  const u16* s_msta  = (const u16*)(lds + LM_MSTA);

  // global operand: col=llo -> batch row (dup llo&3), k chunk at lhi*16 (+64)
  const u32 a_off  = (u32)((r0 + (llo & 3)) * 128 + lhi * 16);
  // global D: batch row llo (<4), cols n = r*16 + lhi*4 + j -> 8B store at +32*r
  const u32 st_off = (u32)((r0 + llo) * 128 + lhi * 8);
  // LDS line: 512B = 4 rows x 128B, swizzle byte ^= (row&3)<<4
  const u32 swr  = (u32)((llo & 3) << 4);
  const u32 aL0  = (u32)((llo & 3) * 128 + ((lhi * 16)      ^ swr));
  const u32 aL1  = (u32)((llo & 3) * 128 + ((lhi * 16 + 64) ^ swr));
  const u32 swo  = (u32)((llo & 3) << 4);      // store rows llo<4
  const u32 stL0 = (u32)(llo * 128 + ((      lhi * 8) ^ swo));
  const u32 stL1 = (u32)(llo * 128 + (( 32 + lhi * 8) ^ swo));
  const u32 stL2 = (u32)(llo * 128 + (( 64 + lhi * 8) ^ swo));
  const u32 stL3 = (u32)(llo * 128 + (( 96 + lhi * 8) ^ swo));

  auto load1 = [&](f16x8& d0, f16x8& d1, u64 md, u32 rb) {
    if ((md >> 43) & 1) {
      const char* l1 = lds + rb + (((u32)(md >> 36) & 127u) << 9);
      d0 = *(const f16x8*)(l1 + aL0);
      d1 = *(const f16x8*)(l1 + aL1);
    } else {
      const char* b1 = nodes + ((u64)((u32)md & 2047u) << SLAB_SH) + a_off;
      d0 = *(const f16x8*)(b1);
      d1 = *(const f16x8*)(b1 + 64);
    }
  };
  auto load2 = [&](f16x8& d0, f16x8& d1, u64 md, u32 rb) {
    if ((md >> 51) & 1) {
      const char* l2 = lds + rb + (((u32)(md >> 44) & 127u) << 9);
      d0 = *(const f16x8*)(l2 + aL0);
      d1 = *(const f16x8*)(l2 + aL1);
    } else {
      const char* b2 = nodes + ((u64)(((u32)(md >> 11)) & 2047u) << SLAB_SH) + a_off;
      d0 = *(const f16x8*)(b2);
      d1 = *(const f16x8*)(b2 + 64);
    }
  };
  auto storeR = [&](u64 md, u32 wb, f32x4 c0, f32x4 c1, f32x4 c2, f32x4 c3) {
    f16x4 r0v = { (f16)(c0.x > 0.f ? c0.x : 0.f), (f16)(c0.y > 0.f ? c0.y : 0.f),
                  (f16)(c0.z > 0.f ? c0.z : 0.f), (f16)(c0.w > 0.f ? c0.w : 0.f) };
    f16x4 r1v = { (f16)(c1.x > 0.f ? c1.x : 0.f), (f16)(c1.y > 0.f ? c1.y : 0.f),
                  (f16)(c1.z > 0.f ? c1.z : 0.f), (f16)(c1.w > 0.f ? c1.w : 0.f) };
    f16x4 r2v = { (f16)(c2.x > 0.f ? c2.x : 0.f), (f16)(c2.y > 0.f ? c2.y : 0.f),
                  (f16)(c2.z > 0.f ? c2.z : 0.f), (f16)(c2.w > 0.f ? c2.w : 0.f) };
    f16x4 r3v = { (f16)(c3.x > 0.f ? c3.x : 0.f), (f16)(c3.y > 0.f ? c3.y : 0.f),
                  (f16)(c3.z > 0.f ? c3.z : 0.f), (f16)(c3.w > 0.f ? c3.w : 0.f) };
    if (llo < 4) {
      if ((md >> 59) & 1) {
        char* lp = lds + wb + (((u32)(md >> 52) & 127u) << 9);
        *(f16x4*)(lp + stL0) = r0v;
        *(f16x4*)(lp + stL1) = r1v;
        *(f16x4*)(lp + stL2) = r2v;
        *(f16x4*)(lp + stL3) = r3v;
      }
      if ((md >> 60) & 1) {
        char* st = nodes + (((u64)((md >> 25) & 2047u)) << SLAB_SH) + st_off;
        *(f16x4*)(st)      = r0v;
        *(f16x4*)(st + 32) = r1v;
        *(f16x4*)(st + 64) = r2v;
        *(f16x4*)(st + 96) = r3v;
      }
    }
  };

  for (int L = 1; L <= nlev; ++L) {
    const u32 rb = (u32)(((L - 1) & 1) << 15);   // read buffer (prev level)
    const u32 wb = (u32)((L & 1) << 15);         // write buffer (this level)
    int k0 = (int)s_msta[L * 8 + m];
    int k1 = (int)s_msta[L * 8 + m + 1];
    k0 = __builtin_amdgcn_readfirstlane(k0);
    k1 = __builtin_amdgcn_readfirstlane(k1);
    if (m < 4) {
      for (int k = k0; k < k1; ++k) {
        u64 md = s_sched[k];
        f16x8 a0, a1;
        load1(a0, a1, md, rb);
        f32x4 c0 = B0, c1 = B1, c2 = B2, c3 = B3;
        __builtin_amdgcn_s_setprio(1);
        c0 = MFMA16(W00, a0, c0); c0 = MFMA16(W01, a1, c0);
        c1 = MFMA16(W10, a0, c1); c1 = MFMA16(W11, a1, c1);
        c2 = MFMA16(W20, a0, c2); c2 = MFMA16(W21, a1, c2);
        c3 = MFMA16(W30, a0, c3); c3 = MFMA16(W31, a1, c3);
        __builtin_amdgcn_s_setprio(0);
        storeR(md, wb, c0, c1, c2, c3);
      }
    } else {
      for (int k = k0; k < k1; ++k) {
        u64 md = s_sched[k];
        f16x8 a0, a1, a2, a3;
        load1(a0, a1, md, rb);
        load2(a2, a3, md, rb);
        f32x4 c0 = B0, c1 = B1, c2 = B2, c3 = B3;
        __builtin_amdgcn_s_setprio(1);
        c0 = MFMA16(W00, a0, c0); c0 = MFMA16(W01, a1, c0);
        c0 = MFMA16(W02, a2, c0); c0 = MFMA16(W03, a3, c0);
        c1 = MFMA16(W10, a0, c1); c1 = MFMA16(W11, a1, c1);
        c1 = MFMA16(W12, a2, c1); c1 = MFMA16(W13, a3, c1);
        c2 = MFMA16(W20, a0, c2); c2 = MFMA16(W21, a1, c2);
        c2 = MFMA16(W22, a2, c2); c2 = MFMA16(W23, a3, c2);
        c3 = MFMA16(W30, a0, c3); c3 = MFMA16(W31, a1, c3);
        c3 = MFMA16(W32, a2, c3); c3 = MFMA16(W33, a3, c3);
        __builtin_amdgcn_s_setprio(0);
        storeR(md, wb, c0, c1, c2, c3);
      }
    }
    __syncthreads();   // level boundary: orders LDS lines + global RAW (8 waves only)
  }
}

// ---------------- final: out[b] = nodes[slot1087][b] . final_W + final_b ----------------
__global__ __launch_bounds__(256) void k_final(const float* __restrict__ fw,
                                               const float* __restrict__ fb,
                                               const char* __restrict__ ws,
                                               float* __restrict__ out) {
  __shared__ float s_fw[64];
  int t = threadIdx.x;
  if (t < 64) s_fw[t] = fw[t];
  __syncthreads();
  int b = blockIdx.x * 256 + t;
  const u32* wl = (const u32*)(ws + WS_LEV);
  if (wl[2]) { out[b] = 0.f; return; }
  u32 slot = wl[1];
  const f16x8* last = (const f16x8*)(ws + WS_NODES + ((u64)slot << SLAB_SH) + (u32)b * 128u);
  float acc = fb[0];
  #pragma unroll
  for (int q = 0; q < 8; ++q) {
    f16x8 v = last[q];
    #pragma unroll
    for (int e = 0; e < 8; ++e) acc += (float)v[e] * s_fw[q * 8 + e];
  }
  out[b] = acc;
}

extern "C" void kernel_launch(void* const* d_in, const int* in_sizes, int n_in,
                              void* d_out, int out_size, void* d_ws, size_t ws_size,
                              hipStream_t stream) {
  const int*   ids = (const int*)d_in[0];
  const int*   wx  = (const int*)d_in[1];
  const int*   i1  = (const int*)d_in[2];
  const int*   i2  = (const int*)d_in[3];
  const float* emb = (const float*)d_in[4];
  const float* oW  = (const float*)d_in[5];
  const float* ob  = (const float*)d_in[6];
  const float* tW  = (const float*)d_in[7];
  const float* tb  = (const float*)d_in[8];
  const float* fw  = (const float*)d_in[9];
  const float* fb  = (const float*)d_in[10];
  char* ws = (char*)d_ws;
  float* out = (float*)d_out;

  int cap = (int)((ws_size > (size_t)WS_NODES) ? ((ws_size - WS_NODES) >> SLAB_SH) : 0);
  if (cap < 80) return;
  if (cap > 2047) cap = 2047;

  hipLaunchKernelGGL(k_sched,   dim3(1),   dim3(1024), 0, stream, wx, i1, i2, ws, cap);
  hipLaunchKernelGGL(k_weights, dim3(64),  dim3(256),  0, stream, oW, ob, tW, tb, ws);
  hipLaunchKernelGGL(k_leaves,  dim3(512), dim3(256),  0, stream, ids, emb, ws);
  hipLaunchKernelGGL(k_main,    dim3(512), dim3(512),  LM_TOTAL, stream, ws);
  hipLaunchKernelGGL(k_final,   dim3(8),   dim3(256),  0, stream, fw, fb, ws, out);
}

// Round 15
// 160.800 us; speedup vs baseline: 2.3880x; 1.3636x over previous
//
#include <hip/hip_runtime.h>

// ---- problem constants ----
#define NIN 64
#define NOPS 1024
#define NB 2048
#define NNODES 1088            // NIN + NOPS
#define SLAB_SH 18             // node slot stride = 2048 rows * 128 B = 1<<18

// ---- workspace layout (bytes) ----
#define WS_SCHED 0u            // u64[1024] packed ops, sorted by (level, mat)
#define WS_LEV   8192u         // u32: [0]=nlev, [1]=slot of node 1087, [2]=err; +4096: u16 msta[2048]
#define WS_WT    16384u        // f16[8][64][128]  ([mat][n][k]), one-input mats zero-padded k>=64
#define WS_BIAS  147456u       // f32[512]
#define WS_NODES 163840u       // f16[cap][2048][64] slot slabs

typedef unsigned int u32;
typedef unsigned short u16;
typedef unsigned long long u64;
typedef _Float16 f16;
typedef _Float16 f16x8 __attribute__((ext_vector_type(8)));
typedef _Float16 f16x4 __attribute__((ext_vector_type(4)));
typedef float f32x4 __attribute__((ext_vector_type(4)));

#define MFMA16(a, b, c) __builtin_amdgcn_mfma_f32_16x16x32_f16((a), (b), (c), 0, 0, 0)

// sched word bits used by k_main: 0-10 slot1 | 11-21 slot2 | 25-35 outslot

// ---------------- schedule: levels + (level,mat) sort + liveness slot allocation ----------------
__global__ __launch_bounds__(1024) void k_sched(const int* __restrict__ wxv,
                                                const int* __restrict__ in1v,
                                                const int* __restrict__ in2v,
                                                char* __restrict__ ws, int cap) {
  __shared__ int s1[NOPS], s2[NOPS], sw[NOPS], slv[NOPS];
  __shared__ int lcnt[132];
  __shared__ int cnt2[1032];
  __shared__ u64 s_pack[NOPS];
  __shared__ int dl[NNODES], slot_of[NNODES], stk[NNODES];
  __shared__ int s_flag, s_nlev, s_top, s_next;
  const int j = threadIdx.x;
  s1[j] = in1v[j]; s2[j] = in2v[j]; sw[j] = wxv[j]; slv[j] = 1;
  if (j < 132) lcnt[j] = 0;
  if (j < 1032) cnt2[j] = 0;
  __syncthreads();
  // monotone relaxation: lvl[j] = 1 + max(lvl(parents)); one-input ops depend only on in1
  for (int it = 0; it < NOPS + 1; ++it) {
    if (j == 0) s_flag = 0;
    __syncthreads();
    int p1 = s1[j];
    int l1 = (p1 >= NIN) ? slv[p1 - NIN] : 0;
    int l2 = 0;
    if (sw[j] >= 4) { int p2 = s2[j]; l2 = (p2 >= NIN) ? slv[p2 - NIN] : 0; }
    int nl = 1 + (l1 > l2 ? l1 : l2);
    if (nl != slv[j]) { slv[j] = nl; s_flag = 1; }
    __syncthreads();
    int f = s_flag;
    __syncthreads();
    if (!f) break;
  }
  if (j == 0) s_nlev = 0;
  __syncthreads();
  atomicMax(&s_nlev, slv[j]);
  __syncthreads();
  u32* wl = (u32*)(ws + WS_LEV);
  const int nlev = s_nlev;
  if (nlev > 127) { if (j == 0) { wl[0] = 0; wl[1] = 0; wl[2] = 1; } return; }
  atomicAdd(&lcnt[slv[j]], 1);
  atomicAdd(&cnt2[slv[j] * 8 + sw[j]], 1);
  __syncthreads();
  if (j == 0) {
    int acc = 0;
    for (int L = 1; L <= nlev; ++L) { int c = lcnt[L]; lcnt[L] = acc; acc += c; }  // level bases
  }
  __syncthreads();
  int base = -1;
  if (j >= 8 && j < (nlev + 1) * 8) {
    int L = j >> 3, mm = j & 7;
    int s = lcnt[L];
    for (int q = 0; q < mm; ++q) s += cnt2[L * 8 + q];
    base = s;
  }
  u16* msta = (u16*)(ws + WS_LEV + 4096);
  for (int t = j; t < 2048; t += 1024) msta[t] = (u16)NOPS;
  __syncthreads();
  if (base >= 0) { cnt2[j] = base; msta[j] = (u16)base; }   // cnt2 becomes the cursor
  __syncthreads();
  { int slot = atomicAdd(&cnt2[slv[j] * 8 + sw[j]], 1);
    u64 p = (u64)(u32)s1[j] | ((u64)(u32)s2[j] << 11) | ((u64)(u32)sw[j] << 22) | ((u64)(u32)j << 25);
    s_pack[slot] = p; }
  // death levels
  for (int t = j; t < NNODES; t += 1024) dl[t] = (t < NIN) ? 0 : slv[t - NIN];
  __syncthreads();
  atomicMax(&dl[s1[j]], slv[j]);
  if (sw[j] >= 4) atomicMax(&dl[s2[j]], slv[j]);
  __syncthreads();
  if (j == 0) { dl[NNODES - 1] = nlev + 1; s_top = 0; s_next = NIN; }
  if (j < NIN) slot_of[j] = j;
  __syncthreads();
  // greedy interval-coloring by level: free (dl == L-1) then allocate (slv == L)
  for (int L = 1; L <= nlev; ++L) {
    for (int t = j; t < NNODES; t += 1024)
      if (dl[t] == L - 1) { int p = atomicAdd(&s_top, 1); stk[p] = slot_of[t]; }
    __syncthreads();
    if (slv[j] == L) {
      int p = atomicSub(&s_top, 1);
      int s;
      if (p >= 1) s = stk[p - 1]; else s = atomicAdd(&s_next, 1);
      slot_of[NIN + j] = s;
    }
    __syncthreads();
    if (j == 0 && s_top < 0) s_top = 0;
    __syncthreads();
  }
  // rewrite schedule entries with slot indices
  {
    u64 m = s_pack[j];
    int i1n = (int)(m & 2047u), i2n = (int)((m >> 11) & 2047u);
    u32 wxn = (u32)((m >> 22) & 7u);
    int opn = (int)((m >> 25) & 2047u);
    if (wxn < 4) i2n = i1n;           // one-input: i2:=i1 (guaranteed-live slot)
    u32 s1slot = (u32)slot_of[i1n];
    u32 s2slot = (u32)slot_of[i2n];
    u64 nm = (u64)s1slot | ((u64)s2slot << 11) | ((u64)wxn << 22)
           | ((u64)(u32)slot_of[NIN + opn] << 25);
    ((u64*)(ws + WS_SCHED))[j] = nm;
  }
  if (j == 0) {
    wl[0] = (u32)nlev;
    wl[1] = (u32)slot_of[NNODES - 1];
    wl[2] = (s_next > cap) ? 1u : 0u;
  }
}

// ---------------- weights: unify + zero-pad + transpose to [mat][n][k], fp16 ----------------
__global__ __launch_bounds__(256) void k_weights(const float* __restrict__ oW,
                                                 const float* __restrict__ ob,
                                                 const float* __restrict__ tW,
                                                 const float* __restrict__ tb,
                                                 char* __restrict__ ws) {
  f16* wt = (f16*)(ws + WS_WT);
  int t = blockIdx.x * 256 + threadIdx.x;
  #pragma unroll
  for (int q = 0; q < 4; ++q) {
    int e = t * 4 + q;                       // e = mat*8192 + n*128 + k
    int mat = e >> 13, n = (e >> 7) & 63, k = e & 127;
    float v;
    if (mat < 4) v = (k < 64) ? oW[mat * 4096 + k * 64 + n] : 0.f;
    else         v = tW[(mat - 4) * 8192 + k * 64 + n];
    wt[e] = (f16)v;
  }
  if (blockIdx.x == 0) {
    float* bs = (float*)(ws + WS_BIAS);
    for (int q = threadIdx.x; q < 512; q += 256)
      bs[q] = (q < 256) ? ob[q] : tb[q - 256];
  }
}

// ---------------- leaves: embedding gather -> slots 0..63 (fp16, vectorized) ----------------
__global__ __launch_bounds__(256) void k_leaves(const int* __restrict__ ids,
                                                const float* __restrict__ emb,
                                                char* __restrict__ ws) {
  int p = blockIdx.x * 256 + threadIdx.x;      // 131072 (i,b) pairs
  int i = p >> 11, b = p & 2047;
  int id = ids[b * 64 + i];
  const f32x4* src = (const f32x4*)(emb + (u32)id * 64u);
  f16x8* dst = (f16x8*)(ws + WS_NODES + ((u32)i << SLAB_SH) + (u32)b * 128u);
  #pragma unroll
  for (int q = 0; q < 8; ++q) {
    f32x4 lo = src[2 * q], hi = src[2 * q + 1];
    f16x8 v = { (f16)lo.x, (f16)lo.y, (f16)lo.z, (f16)lo.w,
                (f16)hi.x, (f16)hi.y, (f16)hi.z, (f16)hi.w };
    dst[q] = v;
  }
}

// ---------------- main: 4-op-packed MFMA columns, all-global, 512x512, 2 blocks/CU ----------------
__global__ __launch_bounds__(512, 4) void k_main(char* __restrict__ ws) {
  __shared__ u64 s_sched[NOPS];   // 8 KB
  __shared__ u16 s_msta[2048];    // 4 KB
  const int tid = threadIdx.x;
  const u32* wl = (const u32*)(ws + WS_LEV);
  if (wl[2]) return;               // uniform early-out before any barrier
  for (int t = tid; t < NOPS; t += 512)
    s_sched[t] = ((const u64*)(ws + WS_SCHED))[t];
  for (int t = tid; t < 1024; t += 512)
    ((u32*)s_msta)[t] = ((const u32*)(ws + WS_LEV + 4096))[t];
  const int nlev = (int)wl[0];

  const int lane   = tid & 63;
  const int m      = tid >> 6;     // 8 waves, wave = its matrix (m<4 => one-input)
  const int lhi    = lane >> 4, llo = lane & 15;
  const int op_sub = llo >> 2;     // which of 4 packed ops this lane's column serves
  const int brow   = llo & 3;      // batch row within block
  const int r0     = blockIdx.x * 4;  // 512 blocks x 4 batch rows
  char* nodes = ws + WS_NODES;

  // W cache: FULL (64 cols x 128 k) slice of mat m; one-input waves only k<64 half
  const f16* wp = (const f16*)(ws + WS_WT) + m * 8192 + llo * 128 + lhi * 8;
  const f16x8 W00 = *(const f16x8*)(wp +        0), W01 = *(const f16x8*)(wp +       32),
              W10 = *(const f16x8*)(wp + 2048 + 0), W11 = *(const f16x8*)(wp + 2048 + 32),
              W20 = *(const f16x8*)(wp + 4096 + 0), W21 = *(const f16x8*)(wp + 4096 + 32),
              W30 = *(const f16x8*)(wp + 6144 + 0), W31 = *(const f16x8*)(wp + 6144 + 32);
  f16x8 W02 = {}, W03 = {}, W12 = {}, W13 = {}, W22 = {}, W23 = {}, W32 = {}, W33 = {};
  if (m >= 4) {
    W02 = *(const f16x8*)(wp +        64); W03 = *(const f16x8*)(wp +        96);
    W12 = *(const f16x8*)(wp + 2048 + 64); W13 = *(const f16x8*)(wp + 2048 + 96);
    W22 = *(const f16x8*)(wp + 4096 + 64); W23 = *(const f16x8*)(wp + 4096 + 96);
    W32 = *(const f16x8*)(wp + 6144 + 64); W33 = *(const f16x8*)(wp + 6144 + 96);
  }
  const float* bsp = (const float*)(ws + WS_BIAS) + m * 64 + lhi * 4;
  const f32x4 B0 = *(const f32x4*)(bsp),      B1 = *(const f32x4*)(bsp + 16),
              B2 = *(const f32x4*)(bsp + 32), B3 = *(const f32x4*)(bsp + 48);
  __syncthreads();

  // per-lane operand source: batch row brow, k chunk lhi
  const u32 a_off  = (u32)((r0 + brow) * 128 + lhi * 16);
  // per-lane D: batch row brow of this lane's op; cols n = r*16 + lhi*4 + j
  const u32 st_off = (u32)((r0 + brow) * 128 + lhi * 8);

  for (int L = 1; L <= nlev; ++L) {
    int k0 = (int)s_msta[L * 8 + m];
    int k1 = (int)s_msta[L * 8 + m + 1];
    k0 = __builtin_amdgcn_readfirstlane(k0);
    k1 = __builtin_amdgcn_readfirstlane(k1);
    const int ke = k1 - 1;
    if (m < 4) {
      for (int g = k0; g < k1; g += 4) {       // 4 ops per iteration (packed in columns)
        int kop = g + op_sub; kop = kop > ke ? ke : kop;   // per-lane clamp (dup = benign)
        u64 md = s_sched[kop];
        const char* b1 = nodes + ((u64)((u32)md & 2047u) << SLAB_SH) + a_off;
        f16x8 a0 = *(const f16x8*)(b1);
        f16x8 a1 = *(const f16x8*)(b1 + 64);
        f32x4 c0 = B0, c1 = B1, c2 = B2, c3 = B3;
        __builtin_amdgcn_s_setprio(1);
        c0 = MFMA16(W00, a0, c0); c0 = MFMA16(W01, a1, c0);
        c1 = MFMA16(W10, a0, c1); c1 = MFMA16(W11, a1, c1);
        c2 = MFMA16(W20, a0, c2); c2 = MFMA16(W21, a1, c2);
        c3 = MFMA16(W30, a0, c3); c3 = MFMA16(W31, a1, c3);
        __builtin_amdgcn_s_setprio(0);
        f16x4 r0v = { (f16)(c0.x > 0.f ? c0.x : 0.f), (f16)(c0.y > 0.f ? c0.y : 0.f),
                      (f16)(c0.z > 0.f ? c0.z : 0.f), (f16)(c0.w > 0.f ? c0.w : 0.f) };
        f16x4 r1v = { (f16)(c1.x > 0.f ? c1.x : 0.f), (f16)(c1.y > 0.f ? c1.y : 0.f),
                      (f16)(c1.z > 0.f ? c1.z : 0.f), (f16)(c1.w > 0.f ? c1.w : 0.f) };
        f16x4 r2v = { (f16)(c2.x > 0.f ? c2.x : 0.f), (f16)(c2.y > 0.f ? c2.y : 0.f),
                      (f16)(c2.z > 0.f ? c2.z : 0.f), (f16)(c2.w > 0.f ? c2.w : 0.f) };
        f16x4 r3v = { (f16)(c3.x > 0.f ? c3.x : 0.f), (f16)(c3.y > 0.f ? c3.y : 0.f),
                      (f16)(c3.z > 0.f ? c3.z : 0.f), (f16)(c3.w > 0.f ? c3.w : 0.f) };
        char* st = nodes + (((u64)((md >> 25) & 2047u)) << SLAB_SH) + st_off;
        *(f16x4*)(st)      = r0v;
        *(f16x4*)(st + 32) = r1v;
        *(f16x4*)(st + 64) = r2v;
        *(f16x4*)(st + 96) = r3v;
      }
    } else {
      for (int g = k0; g < k1; g += 4) {
        int kop = g + op_sub; kop = kop > ke ? ke : kop;
        u64 md = s_sched[kop];
        const char* b1 = nodes + ((u64)((u32)md & 2047u) << SLAB_SH) + a_off;
        const char* b2 = nodes + ((u64)(((u32)(md >> 11)) & 2047u) << SLAB_SH) + a_off;
        f16x8 a0 = *(const f16x8*)(b1);
        f16x8 a1 = *(const f16x8*)(b1 + 64);
        f16x8 a2 = *(const f16x8*)(b2);
        f16x8 a3 = *(const f16x8*)(b2 + 64);
        f32x4 c0 = B0, c1 = B1, c2 = B2, c3 = B3;
        __builtin_amdgcn_s_setprio(1);
        c0 = MFMA16(W00, a0, c0); c0 = MFMA16(W01, a1, c0);
        c0 = MFMA16(W02, a2, c0); c0 = MFMA16(W03, a3, c0);
        c1 = MFMA16(W10, a0, c1); c1 = MFMA16(W11, a1, c1);
        c1 = MFMA16(W12, a2, c1); c1 = MFMA16(W13, a3, c1);
        c2 = MFMA16(W20, a0, c2); c2 = MFMA16(W21, a1, c2);
        c2 = MFMA16(W22, a2, c2); c2 = MFMA16(W23, a3, c2);
        c3 = MFMA16(W30, a0, c3); c3 = MFMA16(W31, a1, c3);
        c3 = MFMA16(W32, a2, c3); c3 = MFMA16(W33, a3, c3);
        __builtin_amdgcn_s_setprio(0);
        f16x4 r0v = { (f16)(c0.x > 0.f ? c0.x : 0.f), (f16)(c0.y > 0.f ? c0.y : 0.f),
                      (f16)(c0.z > 0.f ? c0.z : 0.f), (f16)(c0.w > 0.f ? c0.w : 0.f) };
        f16x4 r1v = { (f16)(c1.x > 0.f ? c1.x : 0.f), (f16)(c1.y > 0.f ? c1.y : 0.f),
                      (f16)(c1.z > 0.f ? c1.z : 0.f), (f16)(c1.w > 0.f ? c1.w : 0.f) };
        f16x4 r2v = { (f16)(c2.x > 0.f ? c2.x : 0.f), (f16)(c2.y > 0.f ? c2.y : 0.f),
                      (f16)(c2.z > 0.f ? c2.z : 0.f), (f16)(c2.w > 0.f ? c2.w : 0.f) };
        f16x4 r3v = { (f16)(c3.x > 0.f ? c3.x : 0.f), (f16)(c3.y > 0.f ? c3.y : 0.f),
                      (f16)(c3.z > 0.f ? c3.z : 0.f), (f16)(c3.w > 0.f ? c3.w : 0.f) };
        char* st = nodes + (((u64)((md >> 25) & 2047u)) << SLAB_SH) + st_off;
        *(f16x4*)(st)      = r0v;
        *(f16x4*)(st + 32) = r1v;
        *(f16x4*)(st + 64) = r2v;
        *(f16x4*)(st + 96) = r3v;
      }
    }
    __syncthreads();   // level boundary: drains stores (L2-visible), orders RAW (8 waves)
  }
}

// ---------------- final: out[b] = nodes[slot1087][b] . final_W + final_b ----------------
__global__ __launch_bounds__(256) void k_final(const float* __restrict__ fw,
                                               const float* __restrict__ fb,
                                               const char* __restrict__ ws,
                                               float* __restrict__ out) {
  __shared__ float s_fw[64];
  int t = threadIdx.x;
  if (t < 64) s_fw[t] = fw[t];
  __syncthreads();
  int b = blockIdx.x * 256 + t;
  const u32* wl = (const u32*)(ws + WS_LEV);
  if (wl[2]) { out[b] = 0.f; return; }
  u32 slot = wl[1];
  const f16x8* last = (const f16x8*)(ws + WS_NODES + ((u64)slot << SLAB_SH) + (u32)b * 128u);
  float acc = fb[0];
  #pragma unroll
  for (int q = 0; q < 8; ++q) {
    f16x8 v = last[q];
    #pragma unroll
    for (int e = 0; e < 8; ++e) acc += (float)v[e] * s_fw[q * 8 + e];
  }
  out[b] = acc;
}

extern "C" void kernel_launch(void* const* d_in, const int* in_sizes, int n_in,
                              void* d_out, int out_size, void* d_ws, size_t ws_size,
                              hipStream_t stream) {
  const int*   ids = (const int*)d_in[0];
  const int*   wx  = (const int*)d_in[1];
  const int*   i1  = (const int*)d_in[2];
  const int*   i2  = (const int*)d_in[3];
  const float* emb = (const float*)d_in[4];
  const float* oW  = (const float*)d_in[5];
  const float* ob  = (const float*)d_in[6];
  const float* tW  = (const float*)d_in[7];
  const float* tb  = (const float*)d_in[8];
  const float* fw  = (const float*)d_in[9];
  const float* fb  = (const float*)d_in[10];
  char* ws = (char*)d_ws;
  float* out = (float*)d_out;

  int cap = (int)((ws_size > (size_t)WS_NODES) ? ((ws_size - WS_NODES) >> SLAB_SH) : 0);
  if (cap < 80) return;
  if (cap > 2047) cap = 2047;

  hipLaunchKernelGGL(k_sched,   dim3(1),   dim3(1024), 0, stream, wx, i1, i2, ws, cap);
  hipLaunchKernelGGL(k_weights, dim3(64),  dim3(256),  0, stream, oW, ob, tW, tb, ws);
  hipLaunchKernelGGL(k_leaves,  dim3(512), dim3(256),  0, stream, ids, emb, ws);
  hipLaunchKernelGGL(k_main,    dim3(512), dim3(512),  0, stream, ws);
  hipLaunchKernelGGL(k_final,   dim3(8),   dim3(256),  0, stream, fw, fb, ws, out);
}

// Round 16
// 124.002 us; speedup vs baseline: 3.0966x; 1.2968x over previous
//
#include <hip/hip_runtime.h>

// ---- problem constants ----
#define NIN 64
#define NOPS 1024
#define NB 2048
#define NNODES 1088            // NIN + NOPS
#define SLAB_SH 18             // node slot stride = 2048 rows * 128 B = 1<<18

// ---- workspace layout (bytes) ----
#define WS_SCHED 0u            // u64[1024] packed ops, sorted by (level, mat)
#define WS_LEV   8192u         // u32: [0]=nlev, [1]=slot of node 1087, [2]=err; +4096: u16 msta[2048]
#define WS_WT    16384u        // f16[8][64][128]  ([mat][n][k]), one-input mats zero-padded k>=64
#define WS_BIAS  147456u       // f32[512]
#define WS_NODES 163840u       // f16[cap][2048][64] slot slabs

// ---- k_main dynamic LDS layout (bytes) ----
// 2 level-buffers x 64 lines x 512B (4 rows x 64 cols fp16, brow-XOR swizzle) + tables
#define LM_LINES 0u            // 65536
#define LM_SCHED 65536u        // u64[1024] = 8KB
#define LM_MSTA  73728u        // u16[2048] = 4KB
#define LM_TOTAL 77824u        // 76KB -> 2 blocks/CU

typedef unsigned int u32;
typedef unsigned short u16;
typedef unsigned long long u64;
typedef _Float16 f16;
typedef _Float16 f16x8 __attribute__((ext_vector_type(8)));
typedef _Float16 f16x4 __attribute__((ext_vector_type(4)));
typedef float f32x4 __attribute__((ext_vector_type(4)));

#define MFMA16(a, b, c) __builtin_amdgcn_mfma_f32_16x16x32_f16((a), (b), (c), 0, 0, 0)

// sched word bits (R8 layout):
//  0-10 slot1 | 11-21 slot2 | 22-24 wx | 25-35 outslot
//  36-42 pos1, 43 fresh1 | 44-50 pos2, 51 fresh2 | 52-58 outpos, 59 ldsout | 60 globalout

// ---------------- schedule: levels + (level,mat) sort + liveness slots + LDS-edge marking ----------------
__global__ __launch_bounds__(1024) void k_sched(const int* __restrict__ wxv,
                                                const int* __restrict__ in1v,
                                                const int* __restrict__ in2v,
                                                char* __restrict__ ws, int cap) {
  __shared__ int s1[NOPS], s2[NOPS], sw[NOPS], slv[NOPS];
  __shared__ int lcnt[132];
  __shared__ int cnt2[1032];
  __shared__ u64 s_pack[NOPS];
  __shared__ int dl[NNODES], slot_of[NNODES], stk[NNODES];
  __shared__ int opPos[NOPS];
  __shared__ unsigned char needG[NOPS];
  __shared__ int s_flag, s_nlev, s_top, s_next;
  const int j = threadIdx.x;
  s1[j] = in1v[j]; s2[j] = in2v[j]; sw[j] = wxv[j]; slv[j] = 1;
  needG[j] = 0;
  if (j < 132) lcnt[j] = 0;
  if (j < 1032) cnt2[j] = 0;
  __syncthreads();
  for (int it = 0; it < NOPS + 1; ++it) {
    if (j == 0) s_flag = 0;
    __syncthreads();
    int p1 = s1[j];
    int l1 = (p1 >= NIN) ? slv[p1 - NIN] : 0;
    int l2 = 0;
    if (sw[j] >= 4) { int p2 = s2[j]; l2 = (p2 >= NIN) ? slv[p2 - NIN] : 0; }
    int nl = 1 + (l1 > l2 ? l1 : l2);
    if (nl != slv[j]) { slv[j] = nl; s_flag = 1; }
    __syncthreads();
    int f = s_flag;
    __syncthreads();
    if (!f) break;
  }
  if (j == 0) s_nlev = 0;
  __syncthreads();
  atomicMax(&s_nlev, slv[j]);
  __syncthreads();
  u32* wl = (u32*)(ws + WS_LEV);
  const int nlev = s_nlev;
  if (nlev > 127) { if (j == 0) { wl[0] = 0; wl[1] = 0; wl[2] = 1; } return; }
  atomicAdd(&lcnt[slv[j]], 1);
  atomicAdd(&cnt2[slv[j] * 8 + sw[j]], 1);
  __syncthreads();
  if (j == 0) {
    int acc = 0;
    for (int L = 1; L <= nlev; ++L) { int c = lcnt[L]; lcnt[L] = acc; acc += c; }
  }
  __syncthreads();
  int base = -1;
  if (j >= 8 && j < (nlev + 1) * 8) {
    int L = j >> 3, mm = j & 7;
    int s = lcnt[L];
    for (int q = 0; q < mm; ++q) s += cnt2[L * 8 + q];
    base = s;
  }
  u16* msta = (u16*)(ws + WS_LEV + 4096);
  for (int t = j; t < 2048; t += 1024) msta[t] = (u16)NOPS;
  __syncthreads();
  if (base >= 0) { cnt2[j] = base; msta[j] = (u16)base; }
  __syncthreads();
  { int slot = atomicAdd(&cnt2[slv[j] * 8 + sw[j]], 1);
    u64 p = (u64)(u32)s1[j] | ((u64)(u32)s2[j] << 11) | ((u64)(u32)sw[j] << 22) | ((u64)(u32)j << 25);
    s_pack[slot] = p;
    opPos[j] = slot - lcnt[slv[j]]; }
  __syncthreads();
  if (j == NOPS - 1) needG[j] = 1;
  { int L = slv[j];
    int i1n = s1[j];
    if (i1n >= NIN) { int p = i1n - NIN; if (!(slv[p] == L - 1 && opPos[p] < 64)) needG[p] = 1; }
    if (sw[j] >= 4) {
      int i2n = s2[j];
      if (i2n >= NIN) { int p = i2n - NIN; if (!(slv[p] == L - 1 && opPos[p] < 64)) needG[p] = 1; }
    } }
  for (int t = j; t < NNODES; t += 1024) dl[t] = (t < NIN) ? 0 : slv[t - NIN];
  __syncthreads();
  atomicMax(&dl[s1[j]], slv[j]);
  if (sw[j] >= 4) atomicMax(&dl[s2[j]], slv[j]);
  __syncthreads();
  if (j == 0) { dl[NNODES - 1] = nlev + 1; s_top = 0; s_next = NIN; }
  if (j < NIN) slot_of[j] = j;
  __syncthreads();
  for (int L = 1; L <= nlev; ++L) {
    for (int t = j; t < NNODES; t += 1024)
      if (dl[t] == L - 1) { int p = atomicAdd(&s_top, 1); stk[p] = slot_of[t]; }
    __syncthreads();
    if (slv[j] == L) {
      int p = atomicSub(&s_top, 1);
      int s;
      if (p >= 1) s = stk[p - 1]; else s = atomicAdd(&s_next, 1);
      slot_of[NIN + j] = s;
    }
    __syncthreads();
    if (j == 0 && s_top < 0) s_top = 0;
    __syncthreads();
  }
  {
    u64 m = s_pack[j];
    int i1n = (int)(m & 2047u), i2n = (int)((m >> 11) & 2047u);
    u32 wxn = (u32)((m >> 22) & 7u);
    int opn = (int)((m >> 25) & 2047u);
    int Lop = slv[opn];
    int two = (wxn >= 4);
    if (!two) i2n = i1n;
    u32 f1 = 0, p1 = 0, f2 = 0, p2 = 0;
    if (i1n >= NIN) { int p = i1n - NIN;
      if (slv[p] == Lop - 1 && opPos[p] < 64) { f1 = 1; p1 = (u32)opPos[p]; } }
    if (i2n >= NIN) { int p = i2n - NIN;
      if (slv[p] == Lop - 1 && opPos[p] < 64) { f2 = 1; p2 = (u32)opPos[p]; } }
    u32 op_pos = (u32)opPos[opn];
    u32 ldsout = (op_pos < 64) ? 1u : 0u;
    u32 gout   = needG[opn] ? 1u : 0u;
    u32 s1slot = (u32)slot_of[i1n];
    u32 s2slot = (u32)slot_of[i2n];
    u64 nm = (u64)s1slot | ((u64)s2slot << 11) | ((u64)wxn << 22)
           | ((u64)(u32)slot_of[NIN + opn] << 25)
           | ((u64)p1 << 36) | ((u64)f1 << 43)
           | ((u64)p2 << 44) | ((u64)f2 << 51)
           | ((u64)(op_pos & 63u) << 52) | ((u64)ldsout << 59)
           | ((u64)gout << 60);
    ((u64*)(ws + WS_SCHED))[j] = nm;
  }
  if (j == 0) {
    wl[0] = (u32)nlev;
    wl[1] = (u32)slot_of[NNODES - 1];
    wl[2] = (s_next > cap) ? 1u : 0u;
  }
}

// ---------------- weights: unify + zero-pad + transpose to [mat][n][k], fp16 ----------------
__global__ __launch_bounds__(256) void k_weights(const float* __restrict__ oW,
                                                 const float* __restrict__ ob,
                                                 const float* __restrict__ tW,
                                                 const float* __restrict__ tb,
                                                 char* __restrict__ ws) {
  f16* wt = (f16*)(ws + WS_WT);
  int t = blockIdx.x * 256 + threadIdx.x;
  #pragma unroll
  for (int q = 0; q < 4; ++q) {
    int e = t * 4 + q;                       // e = mat*8192 + n*128 + k
    int mat = e >> 13, n = (e >> 7) & 63, k = e & 127;
    float v;
    if (mat < 4) v = (k < 64) ? oW[mat * 4096 + k * 64 + n] : 0.f;
    else         v = tW[(mat - 4) * 8192 + k * 64 + n];
    wt[e] = (f16)v;
  }
  if (blockIdx.x == 0) {
    float* bs = (float*)(ws + WS_BIAS);
    for (int q = threadIdx.x; q < 512; q += 256)
      bs[q] = (q < 256) ? ob[q] : tb[q - 256];
  }
}

// ---------------- leaves: embedding gather -> slots 0..63 (fp16, vectorized) ----------------
__global__ __launch_bounds__(256) void k_leaves(const int* __restrict__ ids,
                                                const float* __restrict__ emb,
                                                char* __restrict__ ws) {
  int p = blockIdx.x * 256 + threadIdx.x;      // 131072 (i,b) pairs
  int i = p >> 11, b = p & 2047;
  int id = ids[b * 64 + i];
  const f32x4* src = (const f32x4*)(emb + (u32)id * 64u);
  f16x8* dst = (f16x8*)(ws + WS_NODES + ((u32)i << SLAB_SH) + (u32)b * 128u);
  #pragma unroll
  for (int q = 0; q < 8; ++q) {
    f32x4 lo = src[2 * q], hi = src[2 * q + 1];
    f16x8 v = { (f16)lo.x, (f16)lo.y, (f16)lo.z, (f16)lo.w,
                (f16)hi.x, (f16)hi.y, (f16)hi.z, (f16)hi.w };
    dst[q] = v;
  }
}

// ---------------- main: 4-op-packed MFMA + LDS fresh-cache + gout-filtered stores ----------------
__global__ __launch_bounds__(512, 4) void k_main(char* __restrict__ ws) {
  extern __shared__ char lds[];
  const int tid = threadIdx.x;
  const u32* wl = (const u32*)(ws + WS_LEV);
  if (wl[2]) return;               // uniform early-out before any barrier
  for (int t = tid; t < NOPS; t += 512)
    ((u64*)(lds + LM_SCHED))[t] = ((const u64*)(ws + WS_SCHED))[t];
  for (int t = tid; t < 1024; t += 512)
    ((u32*)(lds + LM_MSTA))[t] = ((const u32*)(ws + WS_LEV + 4096))[t];
  const int nlev = (int)wl[0];

  const int lane   = tid & 63;
  const int m      = tid >> 6;     // 8 waves, wave = its matrix (m<4 => one-input)
  const int lhi    = lane >> 4, llo = lane & 15;
  const int op_sub = llo >> 2;     // which of 4 packed ops this lane's column serves
  const int brow   = llo & 3;      // batch row within block
  const int r0     = blockIdx.x * 4;  // 512 blocks x 4 batch rows
  char* nodes = ws + WS_NODES;

  // W cache: FULL (64 cols x 128 k) slice of mat m; one-input waves only k<64 half
  const f16* wp = (const f16*)(ws + WS_WT) + m * 8192 + llo * 128 + lhi * 8;
  const f16x8 W00 = *(const f16x8*)(wp +        0), W01 = *(const f16x8*)(wp +       32),
              W10 = *(const f16x8*)(wp + 2048 + 0), W11 = *(const f16x8*)(wp + 2048 + 32),
              W20 = *(const f16x8*)(wp + 4096 + 0), W21 = *(const f16x8*)(wp + 4096 + 32),
              W30 = *(const f16x8*)(wp + 6144 + 0), W31 = *(const f16x8*)(wp + 6144 + 32);
  f16x8 W02 = {}, W03 = {}, W12 = {}, W13 = {}, W22 = {}, W23 = {}, W32 = {}, W33 = {};
  if (m >= 4) {
    W02 = *(const f16x8*)(wp +        64); W03 = *(const f16x8*)(wp +        96);
    W12 = *(const f16x8*)(wp + 2048 + 64); W13 = *(const f16x8*)(wp + 2048 + 96);
    W22 = *(const f16x8*)(wp + 4096 + 64); W23 = *(const f16x8*)(wp + 4096 + 96);
    W32 = *(const f16x8*)(wp + 6144 + 64); W33 = *(const f16x8*)(wp + 6144 + 96);
  }
  const float* bsp = (const float*)(ws + WS_BIAS) + m * 64 + lhi * 4;
  const f32x4 B0 = *(const f32x4*)(bsp),      B1 = *(const f32x4*)(bsp + 16),
              B2 = *(const f32x4*)(bsp + 32), B3 = *(const f32x4*)(bsp + 48);
  __syncthreads();

  const u64* s_sched = (const u64*)(lds + LM_SCHED);
  const u16* s_msta  = (const u16*)(lds + LM_MSTA);

  // per-lane global operand source: batch row brow, k chunk lhi
  const u32 a_off  = (u32)((r0 + brow) * 128 + lhi * 16);
  // per-lane global D: batch row brow; cols n = r*16 + lhi*4 + j
  const u32 st_off = (u32)((r0 + brow) * 128 + lhi * 8);
  // LDS line: 512B = 4 rows x 128B; data byte (row,c) at row*128 + (c ^ (row<<4))
  const u32 key   = (u32)(brow << 4);
  const u32 aL0   = (u32)(brow * 128 + ((lhi * 16)      ^ key));
  const u32 aL1   = (u32)(brow * 128 + ((lhi * 16 + 64) ^ key));
  const u32 stL0  = (u32)(brow * 128 + ((      lhi * 8) ^ key));
  const u32 stL1  = (u32)(brow * 128 + (( 32 + lhi * 8) ^ key));
  const u32 stL2  = (u32)(brow * 128 + (( 64 + lhi * 8) ^ key));
  const u32 stL3  = (u32)(brow * 128 + (( 96 + lhi * 8) ^ key));

  for (int L = 1; L <= nlev; ++L) {
    const u32 rb = (u32)(((L - 1) & 1) << 15);   // read buffer (prev level)
    const u32 wb = (u32)((L & 1) << 15);         // write buffer (this level)
    int k0 = (int)s_msta[L * 8 + m];
    int k1 = (int)s_msta[L * 8 + m + 1];
    k0 = __builtin_amdgcn_readfirstlane(k0);
    k1 = __builtin_amdgcn_readfirstlane(k1);
    const int ke = k1 - 1;
    for (int g = k0; g < k1; g += 4) {         // 4 ops per iteration (packed in columns)
      int kop = g + op_sub; kop = kop > ke ? ke : kop;   // per-lane clamp (dup = benign)
      u64 md = s_sched[kop];
      // operand 1: fresh -> LDS line, else global (uniform per 16-lane op group)
      f16x8 a0, a1;
      if ((md >> 43) & 1) {
        const char* l1 = lds + rb + (((u32)(md >> 36) & 63u) << 9);
        a0 = *(const f16x8*)(l1 + aL0);
        a1 = *(const f16x8*)(l1 + aL1);
      } else {
        const char* b1 = nodes + ((u64)((u32)md & 2047u) << SLAB_SH) + a_off;
        a0 = *(const f16x8*)(b1);
        a1 = *(const f16x8*)(b1 + 64);
      }
      f16x8 a2 = {}, a3 = {};
      if (m >= 4) {
        if ((md >> 51) & 1) {
          const char* l2 = lds + rb + (((u32)(md >> 44) & 63u) << 9);
          a2 = *(const f16x8*)(l2 + aL0);
          a3 = *(const f16x8*)(l2 + aL1);
        } else {
          const char* b2 = nodes + ((u64)(((u32)(md >> 11)) & 2047u) << SLAB_SH) + a_off;
          a2 = *(const f16x8*)(b2);
          a3 = *(const f16x8*)(b2 + 64);
        }
      }
      f32x4 c0 = B0, c1 = B1, c2 = B2, c3 = B3;
      __builtin_amdgcn_s_setprio(1);
      c0 = MFMA16(W00, a0, c0); c0 = MFMA16(W01, a1, c0);
      c1 = MFMA16(W10, a0, c1); c1 = MFMA16(W11, a1, c1);
      c2 = MFMA16(W20, a0, c2); c2 = MFMA16(W21, a1, c2);
      c3 = MFMA16(W30, a0, c3); c3 = MFMA16(W31, a1, c3);
      if (m >= 4) {
        c0 = MFMA16(W02, a2, c0); c0 = MFMA16(W03, a3, c0);
        c1 = MFMA16(W12, a2, c1); c1 = MFMA16(W13, a3, c1);
        c2 = MFMA16(W22, a2, c2); c2 = MFMA16(W23, a3, c2);
        c3 = MFMA16(W32, a2, c3); c3 = MFMA16(W33, a3, c3);
      }
      __builtin_amdgcn_s_setprio(0);
      f16x4 r0v = { (f16)(c0.x > 0.f ? c0.x : 0.f), (f16)(c0.y > 0.f ? c0.y : 0.f),
                    (f16)(c0.z > 0.f ? c0.z : 0.f), (f16)(c0.w > 0.f ? c0.w : 0.f) };
      f16x4 r1v = { (f16)(c1.x > 0.f ? c1.x : 0.f), (f16)(c1.y > 0.f ? c1.y : 0.f),
                    (f16)(c1.z > 0.f ? c1.z : 0.f), (f16)(c1.w > 0.f ? c1.w : 0.f) };
      f16x4 r2v = { (f16)(c2.x > 0.f ? c2.x : 0.f), (f16)(c2.y > 0.f ? c2.y : 0.f),
                    (f16)(c2.z > 0.f ? c2.z : 0.f), (f16)(c2.w > 0.f ? c2.w : 0.f) };
      f16x4 r3v = { (f16)(c3.x > 0.f ? c3.x : 0.f), (f16)(c3.y > 0.f ? c3.y : 0.f),
                    (f16)(c3.z > 0.f ? c3.z : 0.f), (f16)(c3.w > 0.f ? c3.w : 0.f) };
      if ((md >> 59) & 1) {                    // LDS line (fresh consumers next level)
        char* lp = lds + wb + (((u32)(md >> 52) & 63u) << 9);
        *(f16x4*)(lp + stL0) = r0v;
        *(f16x4*)(lp + stL1) = r1v;
        *(f16x4*)(lp + stL2) = r2v;
        *(f16x4*)(lp + stL3) = r3v;
      }
      if ((md >> 60) & 1) {                    // global copy only when needed
        char* st = nodes + (((u64)((md >> 25) & 2047u)) << SLAB_SH) + st_off;
        *(f16x4*)(st)      = r0v;
        *(f16x4*)(st + 32) = r1v;
        *(f16x4*)(st + 64) = r2v;
        *(f16x4*)(st + 96) = r3v;
      }
    }
    __syncthreads();   // level boundary: drains stores + LDS writes, orders RAW (8 waves)
  }
}

// ---------------- final: out[b] = nodes[slot1087][b] . final_W + final_b ----------------
__global__ __launch_bounds__(256) void k_final(const float* __restrict__ fw,
                                               const float* __restrict__ fb,
                                               const char* __restrict__ ws,
                                               float* __restrict__ out) {
  __shared__ float s_fw[64];
  int t = threadIdx.x;
  if (t < 64) s_fw[t] = fw[t];
  __syncthreads();
  int b = blockIdx.x * 256 + t;
  const u32* wl = (const u32*)(ws + WS_LEV);
  if (wl[2]) { out[b] = 0.f; return; }
  u32 slot = wl[1];
  const f16x8* last = (const f16x8*)(ws + WS_NODES + ((u64)slot << SLAB_SH) + (u32)b * 128u);
  float acc = fb[0];
  #pragma unroll
  for (int q = 0; q < 8; ++q) {
    f16x8 v = last[q];
    #pragma unroll
    for (int e = 0; e < 8; ++e) acc += (float)v[e] * s_fw[q * 8 + e];
  }
  out[b] = acc;
}

extern "C" void kernel_launch(void* const* d_in, const int* in_sizes, int n_in,
                              void* d_out, int out_size, void* d_ws, size_t ws_size,
                              hipStream_t stream) {
  const int*   ids = (const int*)d_in[0];
  const int*   wx  = (const int*)d_in[1];
  const int*   i1  = (const int*)d_in[2];
  const int*   i2  = (const int*)d_in[3];
  const float* emb = (const float*)d_in[4];
  const float* oW  = (const float*)d_in[5];
  const float* ob  = (const float*)d_in[6];
  const float* tW  = (const float*)d_in[7];
  const float* tb  = (const float*)d_in[8];
  const float* fw  = (const float*)d_in[9];
  const float* fb  = (const float*)d_in[10];
  char* ws = (char*)d_ws;
  float* out = (float*)d_out;

  int cap = (int)((ws_size > (size_t)WS_NODES) ? ((ws_size - WS_NODES) >> SLAB_SH) : 0);
  if (cap < 80) return;
  if (cap > 2047) cap = 2047;

  hipLaunchKernelGGL(k_sched,   dim3(1),   dim3(1024), 0, stream, wx, i1, i2, ws, cap);
  hipLaunchKernelGGL(k_weights, dim3(64),  dim3(256),  0, stream, oW, ob, tW, tb, ws);
  hipLaunchKernelGGL(k_leaves,  dim3(512), dim3(256),  0, stream, ids, emb, ws);
  hipLaunchKernelGGL(k_main,    dim3(512), dim3(512),  LM_TOTAL, stream, ws);
  hipLaunchKernelGGL(k_final,   dim3(8),   dim3(256),  0, stream, fw, fb, ws, out);
}

// Round 17
// 120.748 us; speedup vs baseline: 3.1801x; 1.0269x over previous
//
#include <hip/hip_runtime.h>

// ---- problem constants ----
#define NIN 64
#define NOPS 1024
#define NB 2048
#define NNODES 1088            // NIN + NOPS
#define SLAB_SH 18             // node slot stride = 2048 rows * 128 B = 1<<18

// ---- workspace layout (bytes) ----
#define WS_SCHED 0u            // u64[1024] packed ops, sorted by (level, mat)
#define WS_LEV   8192u         // u32: [0]=nlev, [1]=slot of node 1087, [2]=err; +4096: u16 msta[2048]
#define WS_WT    16384u        // f16[8][64][128]  ([mat][n][k]), one-input mats zero-padded k>=64
#define WS_BIAS  147456u       // f32[512]
#define WS_NODES 163840u       // f16[cap][2048][64] slot slabs

// ---- k_main dynamic LDS layout (bytes) ----
// 2 level-buffers x 64 lines x 512B (4 rows x 64 cols fp16, brow/pos-XOR swizzle) + tables
#define LM_LINES 0u            // 65536
#define LM_SCHED 65536u        // u64[1024] = 8KB
#define LM_MSTA  73728u        // u16[2048] = 4KB
#define LM_TOTAL 77824u        // 76KB -> 2 blocks/CU

typedef unsigned int u32;
typedef unsigned short u16;
typedef unsigned long long u64;
typedef _Float16 f16;
typedef _Float16 f16x8 __attribute__((ext_vector_type(8)));
typedef _Float16 f16x4 __attribute__((ext_vector_type(4)));
typedef float f32x4 __attribute__((ext_vector_type(4)));

#define MFMA16(a, b, c) __builtin_amdgcn_mfma_f32_16x16x32_f16((a), (b), (c), 0, 0, 0)

// sched word bits (R8 layout):
//  0-10 slot1 | 11-21 slot2 | 22-24 wx | 25-35 outslot
//  36-42 pos1, 43 fresh1 | 44-50 pos2, 51 fresh2 | 52-58 outpos, 59 ldsout | 60 globalout

// ---------------- schedule: levels + (level,mat) sort + liveness slots + LDS-edge marking ----------------
__global__ __launch_bounds__(1024) void k_sched(const int* __restrict__ wxv,
                                                const int* __restrict__ in1v,
                                                const int* __restrict__ in2v,
                                                char* __restrict__ ws, int cap) {
  __shared__ int s1[NOPS], s2[NOPS], sw[NOPS], slv[NOPS];
  __shared__ int lcnt[132];
  __shared__ int cnt2[1032];
  __shared__ u64 s_pack[NOPS];
  __shared__ int dl[NNODES], slot_of[NNODES];
  __shared__ int stk[2304];
  __shared__ int opPos[NOPS];
  __shared__ unsigned char needG[NOPS];
  __shared__ int s_flags[3];
  __shared__ int s_nlev, s_top, s_err;
  const int j = threadIdx.x;
  s1[j] = in1v[j]; s2[j] = in2v[j]; sw[j] = wxv[j]; slv[j] = 1;
  needG[j] = 0;
  if (j < 132) lcnt[j] = 0;
  if (j < 1032) cnt2[j] = 0;
  if (j < 3) s_flags[j] = 0;
  if (j == 0) { s_nlev = 0; s_err = 0; }
  __syncthreads();
  // monotone relaxation, 1 barrier/iter via 3 rotating flags
  for (int it = 0; it < NOPS + 1; ++it) {
    int c = it % 3;
    int p1 = s1[j];
    int l1 = (p1 >= NIN) ? slv[p1 - NIN] : 0;
    int l2 = 0;
    if (sw[j] >= 4) { int p2 = s2[j]; l2 = (p2 >= NIN) ? slv[p2 - NIN] : 0; }
    int nl = 1 + (l1 > l2 ? l1 : l2);
    if (nl != slv[j]) { slv[j] = nl; s_flags[c] = 1; }
    if (j == 0) s_flags[(it + 1) % 3] = 0;
    __syncthreads();
    if (!s_flags[c]) break;         // uniform
  }
  atomicMax(&s_nlev, slv[j]);
  __syncthreads();
  u32* wl = (u32*)(ws + WS_LEV);
  const int nlev = s_nlev;
  if (nlev > 127) { if (j == 0) { wl[0] = 0; wl[1] = 0; wl[2] = 1; } return; }
  atomicAdd(&lcnt[slv[j]], 1);
  atomicAdd(&cnt2[slv[j] * 8 + sw[j]], 1);
  __syncthreads();
  if (j == 0) {
    int acc = 0;
    for (int L = 1; L <= nlev; ++L) { int c = lcnt[L]; lcnt[L] = acc; acc += c; }
  }
  __syncthreads();
  int base = -1;
  if (j >= 8 && j < (nlev + 1) * 8) {
    int L = j >> 3, mm = j & 7;
    int s = lcnt[L];
    for (int q = 0; q < mm; ++q) s += cnt2[L * 8 + q];
    base = s;
  }
  u16* msta = (u16*)(ws + WS_LEV + 4096);
  for (int t = j; t < 2048; t += 1024) msta[t] = (u16)NOPS;
  __syncthreads();
  if (base >= 0) { cnt2[j] = base; msta[j] = (u16)base; }
  __syncthreads();
  { int slot = atomicAdd(&cnt2[slv[j] * 8 + sw[j]], 1);
    u64 p = (u64)(u32)s1[j] | ((u64)(u32)s2[j] << 11) | ((u64)(u32)sw[j] << 22) | ((u64)(u32)j << 25);
    s_pack[slot] = p;
    opPos[j] = slot - lcnt[slv[j]]; }
  __syncthreads();
  if (j == NOPS - 1) needG[j] = 1;
  { int L = slv[j];
    int i1n = s1[j];
    if (i1n >= NIN) { int p = i1n - NIN; if (!(slv[p] == L - 1 && opPos[p] < 64)) needG[p] = 1; }
    if (sw[j] >= 4) {
      int i2n = s2[j];
      if (i2n >= NIN) { int p = i2n - NIN; if (!(slv[p] == L - 1 && opPos[p] < 64)) needG[p] = 1; }
    } }
  for (int t = j; t < NNODES; t += 1024) dl[t] = (t < NIN) ? 0 : slv[t - NIN];
  __syncthreads();
  atomicMax(&dl[s1[j]], slv[j]);
  if (sw[j] >= 4) atomicMax(&dl[s2[j]], slv[j]);
  __syncthreads();
  if (j == 0) dl[NNODES - 1] = nlev + 1;
  if (j < NIN) slot_of[j] = j;
  // pre-seed free stack with slots 64..64+S-1 (order irrelevant)
  { int S = cap - 64; if (S > 1152) S = 1152;
    for (int t = j; t < S; t += 1024) stk[t] = 64 + t;
    if (j == 0) s_top = S; }
  __syncthreads();
  // coloring: 2 barriers per level (free pushes; alloc pops); underflow -> err
  for (int L = 1; L <= nlev; ++L) {
    for (int t = j; t < NNODES; t += 1024)
      if (dl[t] == L - 1) {
        int p = atomicAdd(&s_top, 1);
        if (p >= 0 && p < 2304) stk[p] = slot_of[t];
      }
    __syncthreads();
    if (slv[j] == L) {
      int p = atomicSub(&s_top, 1);
      int s;
      if (p >= 1) s = stk[p - 1]; else { s = 64; s_err = 1; }
      slot_of[NIN + j] = s;
    }
    __syncthreads();
  }
  {
    u64 m = s_pack[j];
    int i1n = (int)(m & 2047u), i2n = (int)((m >> 11) & 2047u);
    u32 wxn = (u32)((m >> 22) & 7u);
    int opn = (int)((m >> 25) & 2047u);
    int Lop = slv[opn];
    int two = (wxn >= 4);
    if (!two) i2n = i1n;
    u32 f1 = 0, p1 = 0, f2 = 0, p2 = 0;
    if (i1n >= NIN) { int p = i1n - NIN;
      if (slv[p] == Lop - 1 && opPos[p] < 64) { f1 = 1; p1 = (u32)opPos[p]; } }
    if (i2n >= NIN) { int p = i2n - NIN;
      if (slv[p] == Lop - 1 && opPos[p] < 64) { f2 = 1; p2 = (u32)opPos[p]; } }
    u32 op_pos = (u32)opPos[opn];
    u32 ldsout = (op_pos < 64) ? 1u : 0u;
    u32 gout   = needG[opn] ? 1u : 0u;
    u32 s1slot = (u32)slot_of[i1n];
    u32 s2slot = (u32)slot_of[i2n];
    u64 nm = (u64)s1slot | ((u64)s2slot << 11) | ((u64)wxn << 22)
           | ((u64)(u32)slot_of[NIN + opn] << 25)
           | ((u64)p1 << 36) | ((u64)f1 << 43)
           | ((u64)p2 << 44) | ((u64)f2 << 51)
           | ((u64)(op_pos & 63u) << 52) | ((u64)ldsout << 59)
           | ((u64)gout << 60);
    ((u64*)(ws + WS_SCHED))[j] = nm;
  }
  if (j == 0) {
    wl[0] = (u32)nlev;
    wl[1] = (u32)slot_of[NNODES - 1];
    wl[2] = s_err ? 1u : 0u;
  }
}

// ---------------- prep: weights unify/transpose + leaves embedding gather (merged) ----------------
__global__ __launch_bounds__(256) void k_prep(const int* __restrict__ ids,
                                              const float* __restrict__ emb,
                                              const float* __restrict__ oW,
                                              const float* __restrict__ ob,
                                              const float* __restrict__ tW,
                                              const float* __restrict__ tb,
                                              char* __restrict__ ws) {
  // ---- leaves: 512 blocks x 256 thr -> 131072 (i,b) pairs ----
  int p = blockIdx.x * 256 + threadIdx.x;
  int i = p >> 11, b = p & 2047;
  int id = ids[b * 64 + i];
  const f32x4* src = (const f32x4*)(emb + (u32)id * 64u);
  f16x8* dst = (f16x8*)(ws + WS_NODES + ((u32)i << SLAB_SH) + (u32)b * 128u);
  #pragma unroll
  for (int q = 0; q < 8; ++q) {
    f32x4 lo = src[2 * q], hi = src[2 * q + 1];
    f16x8 v = { (f16)lo.x, (f16)lo.y, (f16)lo.z, (f16)lo.w,
                (f16)hi.x, (f16)hi.y, (f16)hi.z, (f16)hi.w };
    dst[q] = v;
  }
  // ---- weights: blocks 0..63 additionally (4 elems/thread) ----
  if (blockIdx.x < 64) {
    f16* wt = (f16*)(ws + WS_WT);
    int t = blockIdx.x * 256 + threadIdx.x;
    #pragma unroll
    for (int q = 0; q < 4; ++q) {
      int e = t * 4 + q;                     // e = mat*8192 + n*128 + k
      int mat = e >> 13, n = (e >> 7) & 63, k = e & 127;
      float v;
      if (mat < 4) v = (k < 64) ? oW[mat * 4096 + k * 64 + n] : 0.f;
      else         v = tW[(mat - 4) * 8192 + k * 64 + n];
      wt[e] = (f16)v;
    }
    if (blockIdx.x == 0) {
      float* bs = (float*)(ws + WS_BIAS);
      for (int q = threadIdx.x; q < 512; q += 256)
        bs[q] = (q < 256) ? ob[q] : tb[q - 256];
    }
  }
}

// ---------------- main: 4-op-packed MFMA + pinned-W regs + LDS fresh-cache ----------------
__global__ __launch_bounds__(512, 4) void k_main(char* __restrict__ ws) {
  extern __shared__ char lds[];
  const int tid = threadIdx.x;
  const u32* wl = (const u32*)(ws + WS_LEV);
  if (wl[2]) return;               // uniform early-out before any barrier
  for (int t = tid; t < NOPS; t += 512)
    ((u64*)(lds + LM_SCHED))[t] = ((const u64*)(ws + WS_SCHED))[t];
  for (int t = tid; t < 1024; t += 512)
    ((u32*)(lds + LM_MSTA))[t] = ((const u32*)(ws + WS_LEV + 4096))[t];
  const int nlev = (int)wl[0];

  const int lane   = tid & 63;
  const int m      = tid >> 6;     // 8 waves, wave = its matrix (m<4 => one-input)
  const int lhi    = lane >> 4, llo = lane & 15;
  const int op_sub = llo >> 2;     // which of 4 packed ops this lane's column serves
  const int brow   = llo & 3;      // batch row within block
  const int r0     = blockIdx.x * 4;  // 512 blocks x 4 batch rows
  char* nodes = ws + WS_NODES;

  // W cache: FULL (64 cols x 128 k) slice of mat m; asm-pinned into VGPRs
  const f16* wp = (const f16*)(ws + WS_WT) + m * 8192 + llo * 128 + lhi * 8;
  f16x8 W00 = *(const f16x8*)(wp +        0), W01 = *(const f16x8*)(wp +       32),
        W10 = *(const f16x8*)(wp + 2048 + 0), W11 = *(const f16x8*)(wp + 2048 + 32),
        W20 = *(const f16x8*)(wp + 4096 + 0), W21 = *(const f16x8*)(wp + 4096 + 32),
        W30 = *(const f16x8*)(wp + 6144 + 0), W31 = *(const f16x8*)(wp + 6144 + 32);
  f16x8 W02 = {}, W03 = {}, W12 = {}, W13 = {}, W22 = {}, W23 = {}, W32 = {}, W33 = {};
  if (m >= 4) {
    W02 = *(const f16x8*)(wp +        64); W03 = *(const f16x8*)(wp +        96);
    W12 = *(const f16x8*)(wp + 2048 + 64); W13 = *(const f16x8*)(wp + 2048 + 96);
    W22 = *(const f16x8*)(wp + 4096 + 64); W23 = *(const f16x8*)(wp + 4096 + 96);
    W32 = *(const f16x8*)(wp + 6144 + 64); W33 = *(const f16x8*)(wp + 6144 + 96);
  }
  // pin: opaque defs -> compiler cannot rematerialize W from memory inside the loop
  asm volatile("" : "+v"(W00), "+v"(W01), "+v"(W10), "+v"(W11),
                    "+v"(W20), "+v"(W21), "+v"(W30), "+v"(W31));
  asm volatile("" : "+v"(W02), "+v"(W03), "+v"(W12), "+v"(W13),
                    "+v"(W22), "+v"(W23), "+v"(W32), "+v"(W33));
  const float* bsp = (const float*)(ws + WS_BIAS) + m * 64 + lhi * 4;
  const f32x4 B0 = *(const f32x4*)(bsp),      B1 = *(const f32x4*)(bsp + 16),
              B2 = *(const f32x4*)(bsp + 32), B3 = *(const f32x4*)(bsp + 48);
  __syncthreads();

  const u64* s_sched = (const u64*)(lds + LM_SCHED);
  const u16* s_msta  = (const u16*)(lds + LM_MSTA);

  // per-lane global operand source: batch row brow, k chunk lhi
  const u32 a_off  = (u32)((r0 + brow) * 128 + lhi * 16);
  // per-lane global D: batch row brow; cols n = r*16 + lhi*4 + j
  const u32 st_off = (u32)((r0 + brow) * 128 + lhi * 8);
  // LDS line: 512B = 4 rows x 128B; byte(row,c) = row*128 + (c ^ (row<<4) ^ ((pos&3)<<5))
  const u32 key  = (u32)(brow << 4);
  const u32 bA   = (u32)(brow * 128);
  const u32 cA0  = (u32)((lhi * 16)      ^ key);
  const u32 cA1  = (u32)((lhi * 16 + 64) ^ key);
  const u32 cS0  = (u32)((      lhi * 8) ^ key);
  const u32 cS1  = (u32)(( 32 + lhi * 8) ^ key);
  const u32 cS2  = (u32)(( 64 + lhi * 8) ^ key);
  const u32 cS3  = (u32)(( 96 + lhi * 8) ^ key);

  for (int L = 1; L <= nlev; ++L) {
    const u32 rb = (u32)(((L - 1) & 1) << 15);   // read buffer (prev level)
    const u32 wb = (u32)((L & 1) << 15);         // write buffer (this level)
    int k0 = (int)s_msta[L * 8 + m];
    int k1 = (int)s_msta[L * 8 + m + 1];
    k0 = __builtin_amdgcn_readfirstlane(k0);
    k1 = __builtin_amdgcn_readfirstlane(k1);
    const int ke = k1 - 1;
    for (int g = k0; g < k1; g += 4) {         // 4 ops per iteration (packed in columns)
      int kop = g + op_sub; kop = kop > ke ? ke : kop;   // per-lane clamp (dup = benign)
      u64 md = s_sched[kop];
      // operand 1: fresh -> LDS line, else global
      f16x8 a0, a1;
      if ((md >> 43) & 1) {
        u32 pos = (u32)(md >> 36) & 63u;
        const char* l1 = lds + rb + (pos << 9);
        u32 px = (pos & 3u) << 5;
        a0 = *(const f16x8*)(l1 + bA + (cA0 ^ px));
        a1 = *(const f16x8*)(l1 + bA + (cA1 ^ px));
      } else {
        const char* b1 = nodes + ((u64)((u32)md & 2047u) << SLAB_SH) + a_off;
        a0 = *(const f16x8*)(b1);
        a1 = *(const f16x8*)(b1 + 64);
      }
      f16x8 a2 = {}, a3 = {};
      if (m >= 4) {
        if ((md >> 51) & 1) {
          u32 pos = (u32)(md >> 44) & 63u;
          const char* l2 = lds + rb + (pos << 9);
          u32 px = (pos & 3u) << 5;
          a2 = *(const f16x8*)(l2 + bA + (cA0 ^ px));
          a3 = *(const f16x8*)(l2 + bA + (cA1 ^ px));
        } else {
          const char* b2 = nodes + ((u64)(((u32)(md >> 11)) & 2047u) << SLAB_SH) + a_off;
          a2 = *(const f16x8*)(b2);
          a3 = *(const f16x8*)(b2 + 64);
        }
      }
      f32x4 c0 = B0, c1 = B1, c2 = B2, c3 = B3;
      __builtin_amdgcn_s_setprio(1);
      c0 = MFMA16(W00, a0, c0); c0 = MFMA16(W01, a1, c0);
      c1 = MFMA16(W10, a0, c1); c1 = MFMA16(W11, a1, c1);
      c2 = MFMA16(W20, a0, c2); c2 = MFMA16(W21, a1, c2);
      c3 = MFMA16(W30, a0, c3); c3 = MFMA16(W31, a1, c3);
      if (m >= 4) {
        c0 = MFMA16(W02, a2, c0); c0 = MFMA16(W03, a3, c0);
        c1 = MFMA16(W12, a2, c1); c1 = MFMA16(W13, a3, c1);
        c2 = MFMA16(W22, a2, c2); c2 = MFMA16(W23, a3, c2);
        c3 = MFMA16(W32, a2, c3); c3 = MFMA16(W33, a3, c3);
      }
      __builtin_amdgcn_s_setprio(0);
      f16x4 r0v = { (f16)(c0.x > 0.f ? c0.x : 0.f), (f16)(c0.y > 0.f ? c0.y : 0.f),
                    (f16)(c0.z > 0.f ? c0.z : 0.f), (f16)(c0.w > 0.f ? c0.w : 0.f) };
      f16x4 r1v = { (f16)(c1.x > 0.f ? c1.x : 0.f), (f16)(c1.y > 0.f ? c1.y : 0.f),
                    (f16)(c1.z > 0.f ? c1.z : 0.f), (f16)(c1.w > 0.f ? c1.w : 0.f) };
      f16x4 r2v = { (f16)(c2.x > 0.f ? c2.x : 0.f), (f16)(c2.y > 0.f ? c2.y : 0.f),
                    (f16)(c2.z > 0.f ? c2.z : 0.f), (f16)(c2.w > 0.f ? c2.w : 0.f) };
      f16x4 r3v = { (f16)(c3.x > 0.f ? c3.x : 0.f), (f16)(c3.y > 0.f ? c3.y : 0.f),
                    (f16)(c3.z > 0.f ? c3.z : 0.f), (f16)(c3.w > 0.f ? c3.w : 0.f) };
      if ((md >> 59) & 1) {                    // LDS line (fresh consumers next level)
        u32 opos = (u32)(md >> 52) & 63u;
        char* lp = lds + wb + (opos << 9);
        u32 px = (opos & 3u) << 5;
        *(f16x4*)(lp + bA + (cS0 ^ px)) = r0v;
        *(f16x4*)(lp + bA + (cS1 ^ px)) = r1v;
        *(f16x4*)(lp + bA + (cS2 ^ px)) = r2v;
        *(f16x4*)(lp + bA + (cS3 ^ px)) = r3v;
      }
      if ((md >> 60) & 1) {                    // global copy only when needed
        char* st = nodes + (((u64)((md >> 25) & 2047u)) << SLAB_SH) + st_off;
        *(f16x4*)(st)      = r0v;
        *(f16x4*)(st + 32) = r1v;
        *(f16x4*)(st + 64) = r2v;
        *(f16x4*)(st + 96) = r3v;
      }
    }
    __syncthreads();   // level boundary: drains stores + LDS writes, orders RAW (8 waves)
  }
}

// ---------------- final: out[b] = nodes[slot1087][b] . final_W + final_b ----------------
__global__ __launch_bounds__(256) void k_final(const float* __restrict__ fw,
                                               const float* __restrict__ fb,
                                               const char* __restrict__ ws,
                                               float* __restrict__ out) {
  __shared__ float s_fw[64];
  int t = threadIdx.x;
  if (t < 64) s_fw[t] = fw[t];
  __syncthreads();
  int b = blockIdx.x * 256 + t;
  const u32* wl = (const u32*)(ws + WS_LEV);
  if (wl[2]) { out[b] = 0.f; return; }
  u32 slot = wl[1];
  const f16x8* last = (const f16x8*)(ws + WS_NODES + ((u64)slot << SLAB_SH) + (u32)b * 128u);
  float acc = fb[0];
  #pragma unroll
  for (int q = 0; q < 8; ++q) {
    f16x8 v = last[q];
    #pragma unroll
    for (int e = 0; e < 8; ++e) acc += (float)v[e] * s_fw[q * 8 + e];
  }
  out[b] = acc;
}

extern "C" void kernel_launch(void* const* d_in, const int* in_sizes, int n_in,
                              void* d_out, int out_size, void* d_ws, size_t ws_size,
                              hipStream_t stream) {
  const int*   ids = (const int*)d_in[0];
  const int*   wx  = (const int*)d_in[1];
  const int*   i1  = (const int*)d_in[2];
  const int*   i2  = (const int*)d_in[3];
  const float* emb = (const float*)d_in[4];
  const float* oW  = (const float*)d_in[5];
  const float* ob  = (const float*)d_in[6];
  const float* tW  = (const float*)d_in[7];
  const float* tb  = (const float*)d_in[8];
  const float* fw  = (const float*)d_in[9];
  const float* fb  = (const float*)d_in[10];
  char* ws = (char*)d_ws;
  float* out = (float*)d_out;

  int cap = (int)((ws_size > (size_t)WS_NODES) ? ((ws_size - WS_NODES) >> SLAB_SH) : 0);
  if (cap < 80) return;
  if (cap > 2047) cap = 2047;

  hipLaunchKernelGGL(k_sched, dim3(1),   dim3(1024), 0, stream, wx, i1, i2, ws, cap);
  hipLaunchKernelGGL(k_prep,  dim3(512), dim3(256),  0, stream, ids, emb, oW, ob, tW, tb, ws);
  hipLaunchKernelGGL(k_main,  dim3(512), dim3(512),  LM_TOTAL, stream, ws);
  hipLaunchKernelGGL(k_final, dim3(8),   dim3(256),  0, stream, fw, fb, ws, out);
}